// Round 5
// baseline (1808.865 us; speedup 1.0000x reference)
//
#include <hip/hip_runtime.h>
#include <stdint.h>

typedef __bf16 bf16x8 __attribute__((ext_vector_type(8)));
typedef float f32x4 __attribute__((ext_vector_type(4)));

#define MFMA16(a, b, c) __builtin_amdgcn_mfma_f32_16x16x32_bf16((a), (b), (c), 0, 0, 0)

__device__ __forceinline__ float sigf(float x) { return 1.f / (1.f + __expf(-x)); }
__device__ __forceinline__ float tanhfast(float x) { return 1.f - 2.f / (__expf(2.f * x) + 1.f); }
__device__ __forceinline__ float bf2f(uint16_t u) {
  union { float f; uint32_t i; } v; v.i = ((uint32_t)u) << 16; return v.f;
}
__device__ __forceinline__ uint16_t f2bf(float f) {
  union { float f; uint32_t i; } v; v.f = f;
  return (uint16_t)((v.i + 0x7FFFu + ((v.i >> 16) & 1u)) >> 16);
}
// 8 consecutive f32 -> bf16x8 (RNE); p must be 16B-aligned
__device__ __forceinline__ bf16x8 cvt8(const float* __restrict__ p) {
  f32x4 a = *(const f32x4*)p;
  f32x4 b = *(const f32x4*)(p + 4);
  bf16x8 r;
  r[0] = (__bf16)a[0]; r[1] = (__bf16)a[1]; r[2] = (__bf16)a[2]; r[3] = (__bf16)a[3];
  r[4] = (__bf16)b[0]; r[5] = (__bf16)b[1]; r[6] = (__bf16)b[2]; r[7] = (__bf16)b[3];
  return r;
}

// ---------------------------------------------------------------------------
// K0: mf_W f32 [512][1000] -> bf16 padded [512][1024]
// ---------------------------------------------------------------------------
__global__ __launch_bounds__(256) void k_prep(
    const float* __restrict__ mf_W, uint16_t* __restrict__ mfWb) {
  const int idx = blockIdx.x * 256 + threadIdx.x;   // 524288 total
  const int h = idx >> 10, k = idx & 1023;
  const float v = (k < 1000) ? mf_W[(size_t)h * 1000 + k] : 0.f;
  mfWb[idx] = f2bf(v);
}

// ---------------------------------------------------------------------------
// K1: encWb[v][col] = bf16( sum_k enc_emb[v][k]*W_ih[col][k] + b_ih + b_hh )
// ---------------------------------------------------------------------------
__global__ __launch_bounds__(256) void k_encW(
    const float* __restrict__ enc_emb,   // [1002][512]
    const float* __restrict__ W_ih,      // [2048][512]
    const float* __restrict__ b_ih,
    const float* __restrict__ b_hh,
    uint16_t* __restrict__ encWb)        // [1002][2048] bf16
{
  const int w = threadIdx.x >> 6, l = threadIdx.x & 63;
  const int mblk = blockIdx.x & 15;
  const int nblk = blockIdx.x >> 4;
  const int kg = l >> 4;
  const int arow = mblk * 64 + w * 16 + (l & 15);
  const bool rowok = arow < 1002;

  f32x4 acc[4] = {};
  for (int kk = 0; kk < 16; ++kk) {
    const int kc = kk * 32 + kg * 8;
    bf16x8 a = {};
    if (rowok) a = cvt8(enc_emb + (size_t)arow * 512 + kc);
#pragma unroll
    for (int n = 0; n < 4; ++n) {
      const int wrow = nblk * 64 + n * 16 + (l & 15);
      bf16x8 b = cvt8(W_ih + (size_t)wrow * 512 + kc);
      acc[n] = MFMA16(a, b, acc[n]);
    }
  }
  const int orow = mblk * 64 + w * 16 + kg * 4;
#pragma unroll
  for (int n = 0; n < 4; ++n) {
    const int col = nblk * 64 + n * 16 + (l & 15);
    const float bias = b_ih[col] + b_hh[col];
#pragma unroll
    for (int j = 0; j < 4; ++j) {
      const int rrow = orow + j;
      if (rrow < 1002) encWb[(size_t)rrow * 2048 + col] = f2bf(acc[n][j] + bias);
    }
  }
}

// ---------------------------------------------------------------------------
// K2: ext GEMM (gathered A, LDS-staged f32->bf16; B = bf16 mfWb in L2)
// ---------------------------------------------------------------------------
__global__ __launch_bounds__(256, 1) void k_ext(
    const int* __restrict__ uid, const int* __restrict__ sid,   // [51200]
    const float* __restrict__ user_emb,    // [50000][500]
    const float* __restrict__ skill_emb,   // [500][500]
    const uint16_t* __restrict__ mfWb,     // [512][1024] bf16
    const float* __restrict__ mf_b,        // [512]
    uint16_t* __restrict__ ext)            // [51200][512] bf16
{
  __shared__ uint16_t As[64 * 40];   // 64 rows, stride 40 bf16 (80B)

  const int tid = threadIdx.x;
  const int w = tid >> 6, l = tid & 63, kg = l >> 4;
  const int mblk = blockIdx.x;

  const int srow = tid >> 2;
  const int kq = (tid & 3) * 8;
  const int m = mblk * 64 + srow;
  const float* up = user_emb + (size_t)uid[m] * 500;
  const float* sp = skill_emb + (size_t)sid[m] * 500;

  f32x4 acc[4][8] = {};

  for (int kk = 0; kk < 32; ++kk) {
    const int e0 = kk * 32 + kq;
    bf16x8 av = {};
    if (e0 + 8 <= 500) {
      av = cvt8(up + e0);
    } else if (e0 == 496) {
      f32x4 a4 = *(const f32x4*)(up + 496);
      f32x4 b4 = *(const f32x4*)sp;
      av[0] = (__bf16)a4[0]; av[1] = (__bf16)a4[1]; av[2] = (__bf16)a4[2]; av[3] = (__bf16)a4[3];
      av[4] = (__bf16)b4[0]; av[5] = (__bf16)b4[1]; av[6] = (__bf16)b4[2]; av[7] = (__bf16)b4[3];
    } else if (e0 < 1000) {
      av = cvt8(sp + (e0 - 500));
    }
    *(bf16x8*)((char*)As + srow * 80 + kq * 2) = av;
    __syncthreads();

    bf16x8 a[4];
#pragma unroll
    for (int rf = 0; rf < 4; ++rf)
      a[rf] = *(const bf16x8*)((char*)As + (rf * 16 + (l & 15)) * 80 + kg * 16);
#pragma unroll
    for (int n = 0; n < 8; ++n) {
      const int col = w * 128 + n * 16 + (l & 15);
      bf16x8 b = *(const bf16x8*)(mfWb + (size_t)col * 1024 + kk * 32 + kg * 8);
#pragma unroll
      for (int rf = 0; rf < 4; ++rf)
        acc[rf][n] = MFMA16(a[rf], b, acc[rf][n]);
    }
    __syncthreads();
  }

#pragma unroll
  for (int rf = 0; rf < 4; ++rf)
#pragma unroll
    for (int n = 0; n < 8; ++n) {
      const int col = w * 128 + n * 16 + (l & 15);
      const float bias = mf_b[col];
#pragma unroll
      for (int j = 0; j < 4; ++j) {
        const int grow = mblk * 64 + rf * 16 + kg * 4 + j;
        ext[(size_t)grow * 512 + col] = f2bf(acc[rf][n][j] + bias);
      }
    }
}

// ---------------------------------------------------------------------------
// K3: persistent LSTM scan — TWO interleaved rowgroups per block (A=g, B=g+8)
//     sharing the same W_hh register fragments. Each half-step: MFMA X ->
//     poll other group's flags -> gather other group's htg -> cell X ->
//     drain -> signal X. The signal RTT + L3 gather of each group hides
//     under the other group's compute phase. grid = 128 blocks.
// ---------------------------------------------------------------------------
__global__ __launch_bounds__(256, 1) void k_scan(
    const int* __restrict__ inp,        // [256][200]
    const float* __restrict__ W_hh,     // [2048][512] f32
    const uint16_t* __restrict__ encWb, // [1002][2048] bf16
    const uint16_t* __restrict__ ext,   // [256*200][512] bf16
    uint16_t* __restrict__ hbuf,        // [2][256][512] bf16
    float* __restrict__ hfinal,         // [256][512] f32
    uint32_t* __restrict__ flags)       // [256] padded x16 (64B stride)
{
  __shared__ uint16_t htgS[2][16 * 512];   // XOR-swizzled rows of 1024B
  __shared__ float gbuf[2][4][16][32];
  __shared__ float ctS[2][16][32];
  __shared__ int inpS[32][200];            // rows 0-15: group A, 16-31: group B

  const int tid = threadIdx.x;
  const int w = tid >> 6, l = tid & 63;   // wave w = gate (i,f,g,o)
  const int gA = blockIdx.x & 7;          // rowgroup A (0..7)
  const int gB = gA + 8;                  // rowgroup B (8..15)
  const int c  = blockIdx.x >> 3;         // h-slice (32 h)
  const int rowA0 = gA * 16, rowB0 = gB * 16;
  const int kg = l >> 4;

  // W_hh slice -> bf16 register fragments (shared by both groups, 128 VGPRs)
  bf16x8 wfrag[16][2];
#pragma unroll
  for (int kk = 0; kk < 16; ++kk) {
#pragma unroll
    for (int n = 0; n < 2; ++n) {
      const int wrow = w * 512 + c * 32 + n * 16 + (l & 15);
      wfrag[kk][n] = cvt8(W_hh + (size_t)wrow * 512 + kk * 32 + kg * 8);
    }
  }
  for (int e = tid; e < 1024; e += 256) ((float*)ctS)[e] = 0.f;
  // htg(0) = 0 for both groups (h0 = 0): zero LDS directly, no hbuf read
  for (int e = tid; e < 4096; e += 256) ((uint64_t*)htgS)[e] = 0ull;
  for (int e = tid; e < 32 * 200; e += 256) {
    const int rr = e / 200, tt = e % 200;
    const int grow = (rr < 16) ? (rowA0 + rr) : (rowB0 + (rr - 16));
    inpS[rr][tt] = inp[grow * 200 + tt];
  }

  // roles for cell-update phase
  const int urr = tid >> 4;             // row within group
  const int uh2 = (tid & 15) << 1;      // 2 consecutive h
  const int ubA = rowA0 + urr, ubB = rowB0 + urr;

  __syncthreads();

  // ---- prologue: acc init (encW gather) for t=0, ext words for t=1
  f32x4 accA[2], accB[2];
#pragma unroll
  for (int n = 0; n < 2; ++n)
#pragma unroll
    for (int j = 0; j < 4; ++j) {
      const int col = w * 512 + c * 32 + n * 16 + (l & 15);
      accA[n][j] = bf2f(encWb[(size_t)inpS[kg * 4 + j][0] * 2048 + col]);
      accB[n][j] = bf2f(encWb[(size_t)inpS[16 + kg * 4 + j][0] * 2048 + col]);
    }
  uint32_t epA = *(const uint32_t*)(ext + (size_t)ubA * 200 * 512 + 512 + c * 32 + uh2);
  uint32_t epB = *(const uint32_t*)(ext + (size_t)ubB * 200 * 512 + 512 + c * 32 + uh2);

// One half-step for group X. Gathers the OTHER group's htg(GT) into htgS[X^1].
#define DO_HALF(X, accX, epX, ubX, gSelf, gOther, PTGT, DOG, GT)                        \
  {                                                                                     \
    const int ar = l & 15;                                                              \
    _Pragma("unroll")                                                                   \
    for (int kk = 0; kk < 16; ++kk) {                                                   \
      bf16x8 a = *(const bf16x8*)((char*)htgS[X] + ar * 1024 +                          \
                                  ((kk * 64 + kg * 16) ^ ((ar & 7) << 4)));             \
      accX[0] = MFMA16(a, wfrag[kk][0], accX[0]);                                       \
      accX[1] = MFMA16(a, wfrag[kk][1], accX[1]);                                       \
    }                                                                                   \
    _Pragma("unroll")                                                                   \
    for (int n = 0; n < 2; ++n)                                                         \
      _Pragma("unroll")                                                                 \
      for (int j = 0; j < 4; ++j)                                                       \
        gbuf[X][w][kg * 4 + j][n * 16 + (l & 15)] = accX[n][j];                         \
    if ((DOG) && w == 0) {                                                              \
      const uint32_t target = (uint32_t)(PTGT);                                         \
      const uint32_t* fb = flags + (gOther) * 256;                                      \
      while (true) {                                                                    \
        uint32_t f = target;                                                            \
        if (l < 16)                                                                     \
          f = __hip_atomic_load(fb + l * 16, __ATOMIC_RELAXED, __HIP_MEMORY_SCOPE_AGENT);\
        if (__all((int)(f >= target))) break;                                           \
        __builtin_amdgcn_s_sleep(1);                                                    \
      }                                                                                 \
    }                                                                                   \
    __syncthreads();                                                                    \
    if (DOG) {                                                                          \
      const uint16_t* hb = hbuf + (size_t)((GT) & 1) * (256 * 512);                     \
      const int yrow0 = (gOther) * 16;                                                  \
      _Pragma("unroll")                                                                 \
      for (int i = 0; i < 8; ++i) {                                                     \
        const int chunk = tid + i * 256;                                                \
        const int rr = chunk >> 7, o8 = chunk & 127;                                    \
        uint64_t v = __hip_atomic_load(                                                 \
            (const uint64_t*)(hb + (size_t)(yrow0 + rr) * 512) + o8,                    \
            __ATOMIC_RELAXED, __HIP_MEMORY_SCOPE_AGENT);                                \
        *(uint64_t*)((char*)htgS[X ^ 1] + rr * 1024 + ((o8 * 8) ^ ((rr & 7) << 4))) = v;\
      }                                                                                 \
    }                                                                                   \
    {                                                                                   \
      float hv[2];                                                                      \
      _Pragma("unroll")                                                                 \
      for (int p = 0; p < 2; ++p) {                                                     \
        const int h = uh2 + p;                                                          \
        const float ig = sigf(gbuf[X][0][urr][h]);                                      \
        const float fg = sigf(gbuf[X][1][urr][h]);                                      \
        const float gg = tanhfast(gbuf[X][2][urr][h]);                                  \
        const float og = sigf(gbuf[X][3][urr][h]);                                      \
        const float cv = fg * ctS[X][urr][h] + ig * gg;                                 \
        ctS[X][urr][h] = cv;                                                            \
        hv[p] = og * tanhfast(cv);                                                      \
      }                                                                                 \
      if (t < 199) {                                                                    \
        const float g0 = sigf(bf2f((uint16_t)(epX & 0xFFFFu)));                         \
        const float g1 = sigf(bf2f((uint16_t)(epX >> 16)));                             \
        const uint32_t pk = (uint32_t)f2bf(hv[0] * g0) | ((uint32_t)f2bf(hv[1] * g1) << 16);\
        uint16_t* hw = hbuf + (size_t)((t + 1) & 1) * (256 * 512) +                     \
                       (size_t)(ubX) * 512 + c * 32 + uh2;                              \
        __hip_atomic_store((uint32_t*)hw, pk, __ATOMIC_RELAXED, __HIP_MEMORY_SCOPE_AGENT);\
      } else {                                                                          \
        hfinal[(size_t)(ubX) * 512 + c * 32 + uh2]     = hv[0];                         \
        hfinal[(size_t)(ubX) * 512 + c * 32 + uh2 + 1] = hv[1];                         \
      }                                                                                 \
    }                                                                                   \
    if (t < 199) {                                                                      \
      const int tn = t + 1;                                                             \
      _Pragma("unroll")                                                                 \
      for (int n = 0; n < 2; ++n)                                                       \
        _Pragma("unroll")                                                               \
        for (int j = 0; j < 4; ++j) {                                                   \
          const int col = w * 512 + c * 32 + n * 16 + (l & 15);                         \
          accX[n][j] = bf2f(encWb[(size_t)inpS[(X ? 16 : 0) + kg * 4 + j][tn] * 2048 + col]);\
        }                                                                               \
      const int te = (t + 2 < 200) ? t + 2 : 199;                                       \
      epX = *(const uint32_t*)(ext + (size_t)(ubX) * 200 * 512 + (size_t)te * 512 + c * 32 + uh2);\
    }                                                                                   \
    asm volatile("s_waitcnt vmcnt(0)" ::: "memory");                                    \
    __syncthreads();                                                                    \
    if (tid == 0)                                                                       \
      __hip_atomic_store(flags + ((gSelf) * 16 + c) * 16, (uint32_t)(t + 1),            \
                         __ATOMIC_RELAXED, __HIP_MEMORY_SCOPE_AGENT);                   \
  }

  for (int t = 0; t < 200; ++t) {
    // A-half: compute A(t); poll B>=t, gather htgB(t)      (skip gather at t=0: zeros)
    DO_HALF(0, accA, epA, ubA, gA, gB, t, (t > 0), t)
    // B-half: compute B(t); poll A>=t+1, gather htgA(t+1)  (skip at t=199)
    DO_HALF(1, accB, epB, ubB, gB, gA, t + 1, (t < 199), t + 1)
  }
#undef DO_HALF
}

// ---------------------------------------------------------------------------
// K4: out[b] = sigmoid( dot(hfinal[b], dec_W[tgt[b]]) + dec_b[tgt[b]] )
// ---------------------------------------------------------------------------
__global__ __launch_bounds__(256) void k_dec(
    const float* __restrict__ hfinal,   // [256][512]
    const float* __restrict__ dec_W,    // [500][512]
    const float* __restrict__ dec_b,    // [500]
    const int* __restrict__ tgt,        // [256]
    float* __restrict__ out)            // [256]
{
  const int w = threadIdx.x >> 6, l = threadIdx.x & 63;
  const int b = blockIdx.x * 4 + w;
  const int t = tgt[b];
  float s = 0.f;
#pragma unroll
  for (int i = 0; i < 8; ++i) {
    const int k = l + i * 64;
    s += hfinal[(size_t)b * 512 + k] * dec_W[(size_t)t * 512 + k];
  }
#pragma unroll
  for (int m = 32; m; m >>= 1) s += __shfl_xor(s, m, 64);
  if (l == 0) out[b] = sigf(s + dec_b[t]);
}

// ---------------------------------------------------------------------------
extern "C" void kernel_launch(void* const* d_in, const int* in_sizes, int n_in,
                              void* d_out, int out_size, void* d_ws, size_t ws_size,
                              hipStream_t stream) {
  (void)in_sizes; (void)n_in; (void)out_size; (void)ws_size;
  const int*   inp       = (const int*)d_in[0];
  const int*   target_id = (const int*)d_in[1];
  const int*   uid       = (const int*)d_in[2];
  const int*   sid       = (const int*)d_in[3];
  // d_in[4] attempt_sequence: unused by reference
  const float* enc_emb   = (const float*)d_in[5];
  const float* user_emb  = (const float*)d_in[6];
  const float* skill_emb = (const float*)d_in[7];
  const float* mf_W      = (const float*)d_in[8];
  const float* mf_b      = (const float*)d_in[9];
  const float* W_ih      = (const float*)d_in[10];
  const float* W_hh      = (const float*)d_in[11];
  const float* b_ih      = (const float*)d_in[12];
  const float* b_hh      = (const float*)d_in[13];
  const float* dec_W     = (const float*)d_in[14];
  const float* dec_b     = (const float*)d_in[15];

  char* ws = (char*)d_ws;
  uint32_t* flags  = (uint32_t*)(ws);                  //    16,384 B (padded flags)
  uint16_t* hbuf   = (uint16_t*)(ws + 16384);          //   524,288 B
  float*    hfinal = (float*)   (ws + 540672);         //   524,288 B
  uint16_t* encWb  = (uint16_t*)(ws + 1064960);        // 4,104,192 B (bf16)
  uint16_t* mfWb   = (uint16_t*)(ws + 5169152);        // 1,048,576 B
  uint16_t* ext    = (uint16_t*)(ws + 6217728);        // 52,428,800 B (total ~58.6 MB)

  // zero flags only (htg(0)=0 handled in-LDS; hbuf fully overwritten in-kernel)
  hipMemsetAsync(ws, 0, 16384, stream);

  k_prep<<<2048, 256, 0, stream>>>(mf_W, mfWb);
  k_encW<<<512,  256, 0, stream>>>(enc_emb, W_ih, b_ih, b_hh, encWb);
  k_ext <<<800,  256, 0, stream>>>(uid, sid, user_emb, skill_emb, mfWb, mf_b, ext);
  k_scan<<<128,  256, 0, stream>>>(inp, W_hh, encWb, ext, hbuf, hfinal, flags);
  k_dec <<<64,   256, 0, stream>>>(hfinal, dec_W, dec_b, target_id, (float*)d_out);
}

// Round 7
// 1551.566 us; speedup vs baseline: 1.1658x; 1.1658x over previous
//
#include <hip/hip_runtime.h>
#include <stdint.h>

typedef __bf16 bf16x8 __attribute__((ext_vector_type(8)));
typedef float f32x4 __attribute__((ext_vector_type(4)));

#define MFMA16(a, b, c) __builtin_amdgcn_mfma_f32_16x16x32_bf16((a), (b), (c), 0, 0, 0)

__device__ __forceinline__ float sigf(float x) { return 1.f / (1.f + __expf(-x)); }
__device__ __forceinline__ float tanhfast(float x) { return 1.f - 2.f / (__expf(2.f * x) + 1.f); }
__device__ __forceinline__ float bf2f(uint16_t u) {
  union { float f; uint32_t i; } v; v.i = ((uint32_t)u) << 16; return v.f;
}
__device__ __forceinline__ uint16_t f2bf(float f) {
  union { float f; uint32_t i; } v; v.f = f;
  return (uint16_t)((v.i + 0x7FFFu + ((v.i >> 16) & 1u)) >> 16);
}
// 8 consecutive f32 -> bf16x8 (RNE); p must be 16B-aligned
__device__ __forceinline__ bf16x8 cvt8(const float* __restrict__ p) {
  f32x4 a = *(const f32x4*)p;
  f32x4 b = *(const f32x4*)(p + 4);
  bf16x8 r;
  r[0] = (__bf16)a[0]; r[1] = (__bf16)a[1]; r[2] = (__bf16)a[2]; r[3] = (__bf16)a[3];
  r[4] = (__bf16)b[0]; r[5] = (__bf16)b[1]; r[6] = (__bf16)b[2]; r[7] = (__bf16)b[3];
  return r;
}

// ---------------------------------------------------------------------------
// K0: mf_W f32 [512][1000] -> bf16 padded [512][1024]
// ---------------------------------------------------------------------------
__global__ __launch_bounds__(256) void k_prep(
    const float* __restrict__ mf_W, uint16_t* __restrict__ mfWb) {
  const int idx = blockIdx.x * 256 + threadIdx.x;   // 524288 total
  const int h = idx >> 10, k = idx & 1023;
  const float v = (k < 1000) ? mf_W[(size_t)h * 1000 + k] : 0.f;
  mfWb[idx] = f2bf(v);
}

// ---------------------------------------------------------------------------
// K1: encWb[v][col] = bf16( sum_k enc_emb[v][k]*W_ih[col][k] + b_ih + b_hh )
// ---------------------------------------------------------------------------
__global__ __launch_bounds__(256) void k_encW(
    const float* __restrict__ enc_emb,   // [1002][512]
    const float* __restrict__ W_ih,      // [2048][512]
    const float* __restrict__ b_ih,
    const float* __restrict__ b_hh,
    uint16_t* __restrict__ encWb)        // [1002][2048] bf16
{
  const int w = threadIdx.x >> 6, l = threadIdx.x & 63;
  const int mblk = blockIdx.x & 15;
  const int nblk = blockIdx.x >> 4;
  const int kg = l >> 4;
  const int arow = mblk * 64 + w * 16 + (l & 15);
  const bool rowok = arow < 1002;

  f32x4 acc[4] = {};
  for (int kk = 0; kk < 16; ++kk) {
    const int kc = kk * 32 + kg * 8;
    bf16x8 a = {};
    if (rowok) a = cvt8(enc_emb + (size_t)arow * 512 + kc);
#pragma unroll
    for (int n = 0; n < 4; ++n) {
      const int wrow = nblk * 64 + n * 16 + (l & 15);
      bf16x8 b = cvt8(W_ih + (size_t)wrow * 512 + kc);
      acc[n] = MFMA16(a, b, acc[n]);
    }
  }
  const int orow = mblk * 64 + w * 16 + kg * 4;
#pragma unroll
  for (int n = 0; n < 4; ++n) {
    const int col = nblk * 64 + n * 16 + (l & 15);
    const float bias = b_ih[col] + b_hh[col];
#pragma unroll
    for (int j = 0; j < 4; ++j) {
      const int rrow = orow + j;
      if (rrow < 1002) encWb[(size_t)rrow * 2048 + col] = f2bf(acc[n][j] + bias);
    }
  }
}

// ---------------------------------------------------------------------------
// K2: ext GEMM (gathered A, LDS-staged f32->bf16; B = bf16 mfWb in L2)
// ---------------------------------------------------------------------------
__global__ __launch_bounds__(256, 1) void k_ext(
    const int* __restrict__ uid, const int* __restrict__ sid,   // [51200]
    const float* __restrict__ user_emb,    // [50000][500]
    const float* __restrict__ skill_emb,   // [500][500]
    const uint16_t* __restrict__ mfWb,     // [512][1024] bf16
    const float* __restrict__ mf_b,        // [512]
    uint16_t* __restrict__ ext)            // [51200][512] bf16
{
  __shared__ uint16_t As[64 * 40];   // 64 rows, stride 40 bf16 (80B)

  const int tid = threadIdx.x;
  const int w = tid >> 6, l = tid & 63, kg = l >> 4;
  const int mblk = blockIdx.x;

  const int srow = tid >> 2;
  const int kq = (tid & 3) * 8;
  const int m = mblk * 64 + srow;
  const float* up = user_emb + (size_t)uid[m] * 500;
  const float* sp = skill_emb + (size_t)sid[m] * 500;

  f32x4 acc[4][8] = {};

  for (int kk = 0; kk < 32; ++kk) {
    const int e0 = kk * 32 + kq;
    bf16x8 av = {};
    if (e0 + 8 <= 500) {
      av = cvt8(up + e0);
    } else if (e0 == 496) {
      f32x4 a4 = *(const f32x4*)(up + 496);
      f32x4 b4 = *(const f32x4*)sp;
      av[0] = (__bf16)a4[0]; av[1] = (__bf16)a4[1]; av[2] = (__bf16)a4[2]; av[3] = (__bf16)a4[3];
      av[4] = (__bf16)b4[0]; av[5] = (__bf16)b4[1]; av[6] = (__bf16)b4[2]; av[7] = (__bf16)b4[3];
    } else if (e0 < 1000) {
      av = cvt8(sp + (e0 - 500));
    }
    *(bf16x8*)((char*)As + srow * 80 + kq * 2) = av;
    __syncthreads();

    bf16x8 a[4];
#pragma unroll
    for (int rf = 0; rf < 4; ++rf)
      a[rf] = *(const bf16x8*)((char*)As + (rf * 16 + (l & 15)) * 80 + kg * 16);
#pragma unroll
    for (int n = 0; n < 8; ++n) {
      const int col = w * 128 + n * 16 + (l & 15);
      bf16x8 b = *(const bf16x8*)(mfWb + (size_t)col * 1024 + kk * 32 + kg * 8);
#pragma unroll
      for (int rf = 0; rf < 4; ++rf)
        acc[rf][n] = MFMA16(a[rf], b, acc[rf][n]);
    }
    __syncthreads();
  }

#pragma unroll
  for (int rf = 0; rf < 4; ++rf)
#pragma unroll
    for (int n = 0; n < 8; ++n) {
      const int col = w * 128 + n * 16 + (l & 15);
      const float bias = mf_b[col];
#pragma unroll
      for (int j = 0; j < 4; ++j) {
        const int grow = mblk * 64 + rf * 16 + kg * 4 + j;
        ext[(size_t)grow * 512 + col] = f2bf(acc[rf][n][j] + bias);
      }
    }
}

// ---------------------------------------------------------------------------
// K3: persistent LSTM scan — POLL-ON-DATA protocol (no flags, no drain).
//     h exchanged as f32 pairs with a 2-bit step-tag ((t>>1)&3) in the even
//     word's mantissa LSBs. Producer: cell -> one tagged 8B relaxed store.
//     Consumer: polls its 16 pairs until tags match -> the poll load IS the
//     gather (one LLC RTT total). hbuf is memset to 0xAA (tag 2) pre-launch
//     (inside the graph, so every replay): first tag-2 poll at any location
//     happens at t>=4, after the same thread observed a tag-1 generation
//     there -> per-location modification-order monotonicity excludes the
//     memset value and all cross-replay staleness. grid = 256 (16rg x 16hs).
//     ROUND-6 BUG FIXED: hbuf store address was missing "+ c*32" (columns
//     32..511 never written -> consumers polled forever -> 600s hang).
// ---------------------------------------------------------------------------
__global__ __launch_bounds__(256, 1) void k_scan(
    const int* __restrict__ inp,        // [256][200]
    const float* __restrict__ W_hh,     // [2048][512] f32
    const uint16_t* __restrict__ encWb, // [1002][2048] bf16
    const uint16_t* __restrict__ ext,   // [256*200][512] bf16
    uint32_t* __restrict__ hbuf,        // [2][256][512] f32-tagged
    float* __restrict__ hfinal)         // [256][512] f32
{
  __shared__ uint16_t htgS[16 * 512];   // XOR-swizzled rows of 1024B
  __shared__ float gbuf[4][16][32];
  __shared__ float ctS[16][32];
  __shared__ int inpS[16][200];

  const int tid = threadIdx.x;
  const int w = tid >> 6, l = tid & 63;   // wave w = gate (i,f,g,o)
  const int c = blockIdx.x & 15;          // h-slice (32 h)
  const int r = blockIdx.x >> 4;          // rowgroup (16 batch rows)
  const int row0 = r * 16;
  const int kg = l >> 4;

  // W_hh slice -> bf16 register fragments (persistent, 128 VGPRs)
  bf16x8 wfrag[16][2];
#pragma unroll
  for (int kk = 0; kk < 16; ++kk) {
#pragma unroll
    for (int n = 0; n < 2; ++n) {
      const int wrow = w * 512 + c * 32 + n * 16 + (l & 15);
      wfrag[kk][n] = cvt8(W_hh + (size_t)wrow * 512 + kk * 32 + kg * 8);
    }
  }
  for (int e = tid; e < 512; e += 256) ctS[e >> 5][e & 31] = 0.f;
  // htg(0) = 0 (h0 = 0): zero LDS directly; no initial hbuf state needed
  for (int e = tid; e < 2048; e += 256) ((uint64_t*)htgS)[e] = 0ull;
  for (int e = tid; e < 16 * 200; e += 256)
    inpS[e / 200][e % 200] = inp[(row0 + e / 200) * 200 + (e % 200)];

  // gather role: row grr, 32 f32 cols starting at gc0 (16 tagged pairs)
  const int grr = tid >> 4;
  const int gc0 = (tid & 15) * 32;
  // cell role: row urr, 2 consecutive h
  const int urr = tid >> 4;
  const int uh2 = (tid & 15) << 1;
  const int ub = row0 + urr;

  __syncthreads();

  // ---- prologue prefetch: acc(t=0) from encWb, ext word for t=1 gate
  f32x4 acc[2];
#pragma unroll
  for (int n = 0; n < 2; ++n)
#pragma unroll
    for (int j = 0; j < 4; ++j) {
      const int col = w * 512 + c * 32 + n * 16 + (l & 15);
      acc[n][j] = bf2f(encWb[(size_t)inpS[kg * 4 + j][0] * 2048 + col]);
    }
  uint32_t ep = *(const uint32_t*)(ext + (size_t)ub * 200 * 512 + 512 + c * 32 + uh2);

  for (int t = 0; t < 200; ++t) {
    // ---- gather h(t): poll tagged data (the poll load IS the data fetch)
    if (t > 0) {
      const uint32_t tag = (uint32_t)((t >> 1) & 3);
      const uint64_t* gp = (const uint64_t*)(hbuf + (size_t)(t & 1) * (256 * 512) +
                                             (size_t)(row0 + grr) * 512 + gc0);
      uint64_t v8[16];
      while (true) {
        bool ok = true;
#pragma unroll
        for (int j = 0; j < 16; ++j)
          v8[j] = __hip_atomic_load(gp + j, __ATOMIC_RELAXED, __HIP_MEMORY_SCOPE_AGENT);
#pragma unroll
        for (int j = 0; j < 16; ++j)
          ok &= (((uint32_t)v8[j] & 3u) == tag);
        if (ok) break;
        __builtin_amdgcn_s_sleep(1);
      }
      // f32 -> bf16, swizzled LDS store (4 x 16B chunks)
#pragma unroll
      for (int k = 0; k < 4; ++k) {
        bf16x8 pk;
#pragma unroll
        for (int j = 0; j < 4; ++j) {
          union { uint32_t u; float f; } lo, hi;
          lo.u = (uint32_t)v8[k * 4 + j];
          hi.u = (uint32_t)(v8[k * 4 + j] >> 32);
          pk[j * 2]     = (__bf16)lo.f;
          pk[j * 2 + 1] = (__bf16)hi.f;
        }
        const int baddr = grr * 1024 + ((((tid & 15) * 64) + k * 16) ^ ((grr & 7) << 4));
        *(bf16x8*)((char*)htgS + baddr) = pk;
      }
    }
    __syncthreads();

    // ---- gates = acc(prefetched encW) + htg @ W_hh_slice^T
    const int ar = l & 15;
#pragma unroll
    for (int kk = 0; kk < 16; ++kk) {
      bf16x8 a = *(const bf16x8*)((char*)htgS + ar * 1024 +
                                  ((kk * 64 + kg * 16) ^ ((ar & 7) << 4)));
      acc[0] = MFMA16(a, wfrag[kk][0], acc[0]);
      acc[1] = MFMA16(a, wfrag[kk][1], acc[1]);
    }
#pragma unroll
    for (int n = 0; n < 2; ++n)
#pragma unroll
      for (int j = 0; j < 4; ++j)
        gbuf[w][kg * 4 + j][n * 16 + (l & 15)] = acc[n][j];
    __syncthreads();

    // ---- cell update: thread -> (row urr, 2 consecutive h); tagged store
    {
      float hv[2];
#pragma unroll
      for (int p = 0; p < 2; ++p) {
        const int h = uh2 + p;
        const float ig = sigf(gbuf[0][urr][h]);
        const float fg = sigf(gbuf[1][urr][h]);
        const float gg = tanhfast(gbuf[2][urr][h]);
        const float og = sigf(gbuf[3][urr][h]);
        const float cv = fg * ctS[urr][h] + ig * gg;
        ctS[urr][h] = cv;
        hv[p] = og * tanhfast(cv);
      }
      if (t < 199) {
        // pre-gate for step t+1: htg = ht * sigmoid(ext[:, t+1, :])
        const float g0 = sigf(bf2f((uint16_t)(ep & 0xFFFFu)));
        const float g1 = sigf(bf2f((uint16_t)(ep >> 16)));
        union { float f; uint32_t u; } w0, w1;
        w0.f = hv[0] * g0; w1.f = hv[1] * g1;
        const uint32_t tagn = (uint32_t)(((t + 1) >> 1) & 3);
        const uint64_t pk64 = (uint64_t)((w0.u & ~3u) | tagn) | ((uint64_t)w1.u << 32);
        // FIX: + c*32 (round 6 omitted it -> cols 32..511 never written -> hang)
        uint64_t* hw = (uint64_t*)(hbuf + (size_t)((t + 1) & 1) * (256 * 512) +
                                   (size_t)ub * 512 + c * 32 + uh2);
        __hip_atomic_store(hw, pk64, __ATOMIC_RELAXED, __HIP_MEMORY_SCOPE_AGENT);
      } else {
        hfinal[(size_t)ub * 512 + c * 32 + uh2]     = hv[0];
        hfinal[(size_t)ub * 512 + c * 32 + uh2 + 1] = hv[1];
      }
    }

    // ---- prefetch for step t+1 (latency hides under next step's poll)
    if (t < 199) {
      const int tn = t + 1;
#pragma unroll
      for (int n = 0; n < 2; ++n)
#pragma unroll
        for (int j = 0; j < 4; ++j) {
          const int col = w * 512 + c * 32 + n * 16 + (l & 15);
          acc[n][j] = bf2f(encWb[(size_t)inpS[kg * 4 + j][tn] * 2048 + col]);
        }
      const int te = (t + 2 < 200) ? t + 2 : 199;
      ep = *(const uint32_t*)(ext + (size_t)ub * 200 * 512 + (size_t)te * 512 + c * 32 + uh2);
    }
  }
}

// ---------------------------------------------------------------------------
// K4: out[b] = sigmoid( dot(hfinal[b], dec_W[tgt[b]]) + dec_b[tgt[b]] )
// ---------------------------------------------------------------------------
__global__ __launch_bounds__(256) void k_dec(
    const float* __restrict__ hfinal,   // [256][512]
    const float* __restrict__ dec_W,    // [500][512]
    const float* __restrict__ dec_b,    // [500]
    const int* __restrict__ tgt,        // [256]
    float* __restrict__ out)            // [256]
{
  const int w = threadIdx.x >> 6, l = threadIdx.x & 63;
  const int b = blockIdx.x * 4 + w;
  const int t = tgt[b];
  float s = 0.f;
#pragma unroll
  for (int i = 0; i < 8; ++i) {
    const int k = l + i * 64;
    s += hfinal[(size_t)b * 512 + k] * dec_W[(size_t)t * 512 + k];
  }
#pragma unroll
  for (int m = 32; m; m >>= 1) s += __shfl_xor(s, m, 64);
  if (l == 0) out[b] = sigf(s + dec_b[t]);
}

// ---------------------------------------------------------------------------
extern "C" void kernel_launch(void* const* d_in, const int* in_sizes, int n_in,
                              void* d_out, int out_size, void* d_ws, size_t ws_size,
                              hipStream_t stream) {
  (void)in_sizes; (void)n_in; (void)out_size; (void)ws_size;
  const int*   inp       = (const int*)d_in[0];
  const int*   target_id = (const int*)d_in[1];
  const int*   uid       = (const int*)d_in[2];
  const int*   sid       = (const int*)d_in[3];
  // d_in[4] attempt_sequence: unused by reference
  const float* enc_emb   = (const float*)d_in[5];
  const float* user_emb  = (const float*)d_in[6];
  const float* skill_emb = (const float*)d_in[7];
  const float* mf_W      = (const float*)d_in[8];
  const float* mf_b      = (const float*)d_in[9];
  const float* W_ih      = (const float*)d_in[10];
  const float* W_hh      = (const float*)d_in[11];
  const float* b_ih      = (const float*)d_in[12];
  const float* b_hh      = (const float*)d_in[13];
  const float* dec_W     = (const float*)d_in[14];
  const float* dec_b     = (const float*)d_in[15];

  char* ws = (char*)d_ws;
  uint32_t* hbuf   = (uint32_t*)(ws);                  // 1,048,576 B (tagged f32 x2 buf)
  float*    hfinal = (float*)   (ws + 1048576);        //   524,288 B
  uint16_t* encWb  = (uint16_t*)(ws + 1572864);        // 4,104,192 B (bf16)
  uint16_t* mfWb   = (uint16_t*)(ws + 5677056);        // 1,048,576 B
  uint16_t* ext    = (uint16_t*)(ws + 6725632);        // 52,428,800 B (total ~59.2 MB)

  // hbuf := 0xAA (tag 2) every call: deterministic first poll sweep + erases
  // all cross-replay state. In-graph, async, ~1MB (negligible).
  hipMemsetAsync(hbuf, 0xAA, 1048576, stream);

  k_prep<<<2048, 256, 0, stream>>>(mf_W, mfWb);
  k_encW<<<512,  256, 0, stream>>>(enc_emb, W_ih, b_ih, b_hh, encWb);
  k_ext <<<800,  256, 0, stream>>>(uid, sid, user_emb, skill_emb, mfWb, mf_b, ext);
  k_scan<<<256,  256, 0, stream>>>(inp, W_hh, encWb, ext, hbuf, hfinal);
  k_dec <<<64,   256, 0, stream>>>(hfinal, dec_W, dec_b, target_id, (float*)d_out);
}

// Round 8
// 1085.138 us; speedup vs baseline: 1.6669x; 1.4298x over previous
//
#include <hip/hip_runtime.h>
#include <stdint.h>

typedef __bf16 bf16x8 __attribute__((ext_vector_type(8)));
typedef float f32x4 __attribute__((ext_vector_type(4)));

#define MFMA16(a, b, c) __builtin_amdgcn_mfma_f32_16x16x32_bf16((a), (b), (c), 0, 0, 0)

__device__ __forceinline__ float sigf(float x) { return 1.f / (1.f + __expf(-x)); }
__device__ __forceinline__ float tanhfast(float x) { return 1.f - 2.f / (__expf(2.f * x) + 1.f); }
__device__ __forceinline__ float bf2f(uint16_t u) {
  union { float f; uint32_t i; } v; v.i = ((uint32_t)u) << 16; return v.f;
}
__device__ __forceinline__ uint16_t f2bf(float f) {
  union { float f; uint32_t i; } v; v.f = f;
  return (uint16_t)((v.i + 0x7FFFu + ((v.i >> 16) & 1u)) >> 16);
}
// 8 consecutive f32 -> bf16x8 (RNE); p must be 16B-aligned
__device__ __forceinline__ bf16x8 cvt8(const float* __restrict__ p) {
  f32x4 a = *(const f32x4*)p;
  f32x4 b = *(const f32x4*)(p + 4);
  bf16x8 r;
  r[0] = (__bf16)a[0]; r[1] = (__bf16)a[1]; r[2] = (__bf16)a[2]; r[3] = (__bf16)a[3];
  r[4] = (__bf16)b[0]; r[5] = (__bf16)b[1]; r[6] = (__bf16)b[2]; r[7] = (__bf16)b[3];
  return r;
}

// ---------------------------------------------------------------------------
// K0: mf_W f32 [512][1000] -> bf16 padded [512][1024]
// ---------------------------------------------------------------------------
__global__ __launch_bounds__(256) void k_prep(
    const float* __restrict__ mf_W, uint16_t* __restrict__ mfWb) {
  const int idx = blockIdx.x * 256 + threadIdx.x;   // 524288 total
  const int h = idx >> 10, k = idx & 1023;
  const float v = (k < 1000) ? mf_W[(size_t)h * 1000 + k] : 0.f;
  mfWb[idx] = f2bf(v);
}

// ---------------------------------------------------------------------------
// K1: encWb[v][col] = bf16( sum_k enc_emb[v][k]*W_ih[col][k] + b_ih + b_hh )
// ---------------------------------------------------------------------------
__global__ __launch_bounds__(256) void k_encW(
    const float* __restrict__ enc_emb,   // [1002][512]
    const float* __restrict__ W_ih,      // [2048][512]
    const float* __restrict__ b_ih,
    const float* __restrict__ b_hh,
    uint16_t* __restrict__ encWb)        // [1002][2048] bf16
{
  const int w = threadIdx.x >> 6, l = threadIdx.x & 63;
  const int mblk = blockIdx.x & 15;
  const int nblk = blockIdx.x >> 4;
  const int kg = l >> 4;
  const int arow = mblk * 64 + w * 16 + (l & 15);
  const bool rowok = arow < 1002;

  f32x4 acc[4] = {};
  for (int kk = 0; kk < 16; ++kk) {
    const int kc = kk * 32 + kg * 8;
    bf16x8 a = {};
    if (rowok) a = cvt8(enc_emb + (size_t)arow * 512 + kc);
#pragma unroll
    for (int n = 0; n < 4; ++n) {
      const int wrow = nblk * 64 + n * 16 + (l & 15);
      bf16x8 b = cvt8(W_ih + (size_t)wrow * 512 + kc);
      acc[n] = MFMA16(a, b, acc[n]);
    }
  }
  const int orow = mblk * 64 + w * 16 + kg * 4;
#pragma unroll
  for (int n = 0; n < 4; ++n) {
    const int col = nblk * 64 + n * 16 + (l & 15);
    const float bias = b_ih[col] + b_hh[col];
#pragma unroll
    for (int j = 0; j < 4; ++j) {
      const int rrow = orow + j;
      if (rrow < 1002) encWb[(size_t)rrow * 2048 + col] = f2bf(acc[n][j] + bias);
    }
  }
}

// ---------------------------------------------------------------------------
// K2: ext GEMM (gathered A, LDS-staged f32->bf16; B = bf16 mfWb in L2)
// ---------------------------------------------------------------------------
__global__ __launch_bounds__(256, 1) void k_ext(
    const int* __restrict__ uid, const int* __restrict__ sid,   // [51200]
    const float* __restrict__ user_emb,    // [50000][500]
    const float* __restrict__ skill_emb,   // [500][500]
    const uint16_t* __restrict__ mfWb,     // [512][1024] bf16
    const float* __restrict__ mf_b,        // [512]
    uint16_t* __restrict__ ext)            // [51200][512] bf16
{
  __shared__ uint16_t As[64 * 40];   // 64 rows, stride 40 bf16 (80B)

  const int tid = threadIdx.x;
  const int w = tid >> 6, l = tid & 63, kg = l >> 4;
  const int mblk = blockIdx.x;

  const int srow = tid >> 2;
  const int kq = (tid & 3) * 8;
  const int m = mblk * 64 + srow;
  const float* up = user_emb + (size_t)uid[m] * 500;
  const float* sp = skill_emb + (size_t)sid[m] * 500;

  f32x4 acc[4][8] = {};

  for (int kk = 0; kk < 32; ++kk) {
    const int e0 = kk * 32 + kq;
    bf16x8 av = {};
    if (e0 + 8 <= 500) {
      av = cvt8(up + e0);
    } else if (e0 == 496) {
      f32x4 a4 = *(const f32x4*)(up + 496);
      f32x4 b4 = *(const f32x4*)sp;
      av[0] = (__bf16)a4[0]; av[1] = (__bf16)a4[1]; av[2] = (__bf16)a4[2]; av[3] = (__bf16)a4[3];
      av[4] = (__bf16)b4[0]; av[5] = (__bf16)b4[1]; av[6] = (__bf16)b4[2]; av[7] = (__bf16)b4[3];
    } else if (e0 < 1000) {
      av = cvt8(sp + (e0 - 500));
    }
    *(bf16x8*)((char*)As + srow * 80 + kq * 2) = av;
    __syncthreads();

    bf16x8 a[4];
#pragma unroll
    for (int rf = 0; rf < 4; ++rf)
      a[rf] = *(const bf16x8*)((char*)As + (rf * 16 + (l & 15)) * 80 + kg * 16);
#pragma unroll
    for (int n = 0; n < 8; ++n) {
      const int col = w * 128 + n * 16 + (l & 15);
      bf16x8 b = *(const bf16x8*)(mfWb + (size_t)col * 1024 + kk * 32 + kg * 8);
#pragma unroll
      for (int rf = 0; rf < 4; ++rf)
        acc[rf][n] = MFMA16(a[rf], b, acc[rf][n]);
    }
    __syncthreads();
  }

#pragma unroll
  for (int rf = 0; rf < 4; ++rf)
#pragma unroll
    for (int n = 0; n < 8; ++n) {
      const int col = w * 128 + n * 16 + (l & 15);
      const float bias = mf_b[col];
#pragma unroll
      for (int j = 0; j < 4; ++j) {
        const int grow = mblk * 64 + rf * 16 + kg * 4 + j;
        ext[(size_t)grow * 512 + col] = f2bf(acc[rf][n][j] + bias);
      }
    }
}

// ---------------------------------------------------------------------------
// K3: persistent LSTM scan — round-4 flag protocol + PER-WAVE INCREMENTAL
//     GATHER. Each wave owns 4 producers: poll flag(p) -> immediately issue
//     that producer's 1KB gather loads (stay in flight under the next poll)
//     -> after all 4 flags, waitcnt + swizzled LDS writes. Removes the
//     single-wave detect + broadcast barrier and overlaps gather with wait.
//     Exchange is bf16 (16KB/rowgroup); flags padded to 64B lines.
//     Writer safety (re-proved): producer overwrites buf[t&1] at cell(t+1),
//     which follows its gather(t+1), which polls peer flags >= t+1, which
//     peers set only after completing their gather(t) of buf[t&1].
// ---------------------------------------------------------------------------
__global__ __launch_bounds__(256, 1) void k_scan(
    const int* __restrict__ inp,        // [256][200]
    const float* __restrict__ W_hh,     // [2048][512] f32
    const uint16_t* __restrict__ encWb, // [1002][2048] bf16
    const uint16_t* __restrict__ ext,   // [256*200][512] bf16
    uint16_t* __restrict__ hbuf,        // [2][256][512] bf16
    float* __restrict__ hfinal,         // [256][512] f32
    uint32_t* __restrict__ flags)       // [256] x 16-u32 stride (64B lines)
{
  __shared__ uint16_t htgS[16 * 512];   // XOR-swizzled rows of 1024B
  __shared__ float gbuf[4][16][32];
  __shared__ float ctS[16][32];
  __shared__ int inpS[16][200];

  const int tid = threadIdx.x;
  const int w = tid >> 6, l = tid & 63;   // wave w = gate (i,f,g,o)
  const int c = blockIdx.x & 15;          // h-slice (32 h)
  const int r = blockIdx.x >> 4;          // rowgroup (16 batch rows)
  const int row0 = r * 16;
  const int kg = l >> 4;

  // W_hh slice -> bf16 register fragments (persistent, 128 VGPRs)
  bf16x8 wfrag[16][2];
#pragma unroll
  for (int kk = 0; kk < 16; ++kk) {
#pragma unroll
    for (int n = 0; n < 2; ++n) {
      const int wrow = w * 512 + c * 32 + n * 16 + (l & 15);
      wfrag[kk][n] = cvt8(W_hh + (size_t)wrow * 512 + kk * 32 + kg * 8);
    }
  }
  for (int e = tid; e < 512; e += 256) ctS[e >> 5][e & 31] = 0.f;
  // htg(0) = 0 (h0 = 0): zero LDS directly
  for (int e = tid; e < 2048; e += 256) ((uint64_t*)htgS)[e] = 0ull;
  for (int e = tid; e < 16 * 200; e += 256)
    inpS[e / 200][e % 200] = inp[(row0 + e / 200) * 200 + (e % 200)];

  // gather role (within wave): row grow_, 16B chunk gch of a producer's 64B row-slice
  const int grow_ = l >> 2;             // 16 rows
  const int gch = l & 3;                // 4 x 16B chunks
  // cell role: row urr, 2 consecutive h
  const int urr = tid >> 4;
  const int uh2 = (tid & 15) << 1;
  const int ub = row0 + urr;

  __syncthreads();

  // ---- prologue prefetch: acc(t=0) from encWb, ext word for t=1 gate
  f32x4 acc[2];
#pragma unroll
  for (int n = 0; n < 2; ++n)
#pragma unroll
    for (int j = 0; j < 4; ++j) {
      const int col = w * 512 + c * 32 + n * 16 + (l & 15);
      acc[n][j] = bf2f(encWb[(size_t)inpS[kg * 4 + j][0] * 2048 + col]);
    }
  uint32_t ep = *(const uint32_t*)(ext + (size_t)ub * 200 * 512 + 512 + c * 32 + uh2);

  for (int t = 0; t < 200; ++t) {
    // ---- per-wave incremental gather of h(t): wave w owns producers 4w..4w+3
    if (t > 0) {
      const uint16_t* hb = hbuf + (size_t)(t & 1) * (256 * 512);
      uint64_t v[4][2];
#pragma unroll
      for (int p = 0; p < 4; ++p) {
        const int prod = w * 4 + p;
        // poll this producer's flag (all lanes same addr -> 1 request/wave)
        while (__hip_atomic_load(flags + (r * 16 + prod) * 16,
                                 __ATOMIC_RELAXED, __HIP_MEMORY_SCOPE_AGENT) < (uint32_t)t)
          __builtin_amdgcn_s_sleep(1);
        // issue this producer's 16B/lane gather (completes under later polls)
        const uint16_t* sp = hb + (size_t)(row0 + grow_) * 512 + prod * 32 + gch * 8;
        v[p][0] = __hip_atomic_load((const uint64_t*)sp,     __ATOMIC_RELAXED, __HIP_MEMORY_SCOPE_AGENT);
        v[p][1] = __hip_atomic_load((const uint64_t*)sp + 1, __ATOMIC_RELAXED, __HIP_MEMORY_SCOPE_AGENT);
      }
      // swizzled LDS writes (bank pattern: 2-way max = free)
#pragma unroll
      for (int p = 0; p < 4; ++p) {
        const int prod = w * 4 + p;
        const int baddr = grow_ * 1024 + (((prod * 64) + gch * 16) ^ ((grow_ & 7) << 4));
        *(uint64_t*)((char*)htgS + baddr)     = v[p][0];
        *(uint64_t*)((char*)htgS + baddr + 8) = v[p][1];
      }
    }
    __syncthreads();

    // ---- gates = acc(prefetched encW) + htg @ W_hh_slice^T
    const int ar = l & 15;
#pragma unroll
    for (int kk = 0; kk < 16; ++kk) {
      bf16x8 a = *(const bf16x8*)((char*)htgS + ar * 1024 +
                                  ((kk * 64 + kg * 16) ^ ((ar & 7) << 4)));
      acc[0] = MFMA16(a, wfrag[kk][0], acc[0]);
      acc[1] = MFMA16(a, wfrag[kk][1], acc[1]);
    }
#pragma unroll
    for (int n = 0; n < 2; ++n)
#pragma unroll
      for (int j = 0; j < 4; ++j)
        gbuf[w][kg * 4 + j][n * 16 + (l & 15)] = acc[n][j];
    __syncthreads();

    // ---- cell update: thread -> (row urr, 2 consecutive h)
    {
      float hv[2];
#pragma unroll
      for (int p = 0; p < 2; ++p) {
        const int h = uh2 + p;
        const float ig = sigf(gbuf[0][urr][h]);
        const float fg = sigf(gbuf[1][urr][h]);
        const float gg = tanhfast(gbuf[2][urr][h]);
        const float og = sigf(gbuf[3][urr][h]);
        const float cv = fg * ctS[urr][h] + ig * gg;
        ctS[urr][h] = cv;
        hv[p] = og * tanhfast(cv);
      }
      if (t < 199) {
        // pre-gate for step t+1: htg = ht * sigmoid(ext[:, t+1, :])
        const float g0 = sigf(bf2f((uint16_t)(ep & 0xFFFFu)));
        const float g1 = sigf(bf2f((uint16_t)(ep >> 16)));
        const uint32_t pk = (uint32_t)f2bf(hv[0] * g0) | ((uint32_t)f2bf(hv[1] * g1) << 16);
        uint32_t* hw = (uint32_t*)(hbuf + (size_t)((t + 1) & 1) * (256 * 512) +
                                   (size_t)ub * 512 + c * 32 + uh2);
        __hip_atomic_store(hw, pk, __ATOMIC_RELAXED, __HIP_MEMORY_SCOPE_AGENT);
      } else {
        hfinal[(size_t)ub * 512 + c * 32 + uh2]     = hv[0];
        hfinal[(size_t)ub * 512 + c * 32 + uh2 + 1] = hv[1];
      }
    }
    // all waves drain stores to the coherence point, then one flag store
    asm volatile("s_waitcnt vmcnt(0)" ::: "memory");
    __syncthreads();
    if (tid == 0)
      __hip_atomic_store(flags + (r * 16 + c) * 16, (uint32_t)(t + 1),
                         __ATOMIC_RELAXED, __HIP_MEMORY_SCOPE_AGENT);

    // ---- prefetch for step t+1 (off the signal path; hides under next poll)
    if (t < 199) {
      const int tn = t + 1;
#pragma unroll
      for (int n = 0; n < 2; ++n)
#pragma unroll
        for (int j = 0; j < 4; ++j) {
          const int col = w * 512 + c * 32 + n * 16 + (l & 15);
          acc[n][j] = bf2f(encWb[(size_t)inpS[kg * 4 + j][tn] * 2048 + col]);
        }
      const int te = (t + 2 < 200) ? t + 2 : 199;
      ep = *(const uint32_t*)(ext + (size_t)ub * 200 * 512 + (size_t)te * 512 + c * 32 + uh2);
    }
  }
}

// ---------------------------------------------------------------------------
// K4: out[b] = sigmoid( dot(hfinal[b], dec_W[tgt[b]]) + dec_b[tgt[b]] )
// ---------------------------------------------------------------------------
__global__ __launch_bounds__(256) void k_dec(
    const float* __restrict__ hfinal,   // [256][512]
    const float* __restrict__ dec_W,    // [500][512]
    const float* __restrict__ dec_b,    // [500]
    const int* __restrict__ tgt,        // [256]
    float* __restrict__ out)            // [256]
{
  const int w = threadIdx.x >> 6, l = threadIdx.x & 63;
  const int b = blockIdx.x * 4 + w;
  const int t = tgt[b];
  float s = 0.f;
#pragma unroll
  for (int i = 0; i < 8; ++i) {
    const int k = l + i * 64;
    s += hfinal[(size_t)b * 512 + k] * dec_W[(size_t)t * 512 + k];
  }
#pragma unroll
  for (int m = 32; m; m >>= 1) s += __shfl_xor(s, m, 64);
  if (l == 0) out[b] = sigf(s + dec_b[t]);
}

// ---------------------------------------------------------------------------
extern "C" void kernel_launch(void* const* d_in, const int* in_sizes, int n_in,
                              void* d_out, int out_size, void* d_ws, size_t ws_size,
                              hipStream_t stream) {
  (void)in_sizes; (void)n_in; (void)out_size; (void)ws_size;
  const int*   inp       = (const int*)d_in[0];
  const int*   target_id = (const int*)d_in[1];
  const int*   uid       = (const int*)d_in[2];
  const int*   sid       = (const int*)d_in[3];
  // d_in[4] attempt_sequence: unused by reference
  const float* enc_emb   = (const float*)d_in[5];
  const float* user_emb  = (const float*)d_in[6];
  const float* skill_emb = (const float*)d_in[7];
  const float* mf_W      = (const float*)d_in[8];
  const float* mf_b      = (const float*)d_in[9];
  const float* W_ih      = (const float*)d_in[10];
  const float* W_hh      = (const float*)d_in[11];
  const float* b_ih      = (const float*)d_in[12];
  const float* b_hh      = (const float*)d_in[13];
  const float* dec_W     = (const float*)d_in[14];
  const float* dec_b     = (const float*)d_in[15];

  char* ws = (char*)d_ws;
  uint32_t* flags  = (uint32_t*)(ws);                  //    16,384 B (padded flags)
  uint16_t* hbuf   = (uint16_t*)(ws + 16384);          //   524,288 B (bf16 x2 buf)
  float*    hfinal = (float*)   (ws + 540672);         //   524,288 B
  uint16_t* encWb  = (uint16_t*)(ws + 1064960);        // 4,104,192 B (bf16)
  uint16_t* mfWb   = (uint16_t*)(ws + 5169152);        // 1,048,576 B
  uint16_t* ext    = (uint16_t*)(ws + 6217728);        // 52,428,800 B (total ~58.6 MB)

  // zero flags every call (in-graph => every replay). hbuf needs no init:
  // gathers are gated by this-run flags; producers write full slices first.
  hipMemsetAsync(flags, 0, 16384, stream);

  k_prep<<<2048, 256, 0, stream>>>(mf_W, mfWb);
  k_encW<<<512,  256, 0, stream>>>(enc_emb, W_ih, b_ih, b_hh, encWb);
  k_ext <<<800,  256, 0, stream>>>(uid, sid, user_emb, skill_emb, mfWb, mf_b, ext);
  k_scan<<<256,  256, 0, stream>>>(inp, W_hh, encWb, ext, hbuf, hfinal, flags);
  k_dec <<<64,   256, 0, stream>>>(hfinal, dec_W, dec_b, target_id, (float*)d_out);
}

// Round 10
// 922.834 us; speedup vs baseline: 1.9601x; 1.1759x over previous
//
#include <hip/hip_runtime.h>
#include <stdint.h>

typedef __bf16 bf16x8 __attribute__((ext_vector_type(8)));
typedef float f32x4 __attribute__((ext_vector_type(4)));

#define MFMA16(a, b, c) __builtin_amdgcn_mfma_f32_16x16x32_bf16((a), (b), (c), 0, 0, 0)

__device__ __forceinline__ float sigf(float x) { return 1.f / (1.f + __expf(-x)); }
__device__ __forceinline__ float tanhfast(float x) { return 1.f - 2.f / (__expf(2.f * x) + 1.f); }
__device__ __forceinline__ float bf2f(uint16_t u) {
  union { float f; uint32_t i; } v; v.i = ((uint32_t)u) << 16; return v.f;
}
__device__ __forceinline__ uint16_t f2bf(float f) {
  union { float f; uint32_t i; } v; v.f = f;
  return (uint16_t)((v.i + 0x7FFFu + ((v.i >> 16) & 1u)) >> 16);
}
// 8 consecutive f32 -> bf16x8 (RNE); p must be 16B-aligned
__device__ __forceinline__ bf16x8 cvt8(const float* __restrict__ p) {
  f32x4 a = *(const f32x4*)p;
  f32x4 b = *(const f32x4*)(p + 4);
  bf16x8 r;
  r[0] = (__bf16)a[0]; r[1] = (__bf16)a[1]; r[2] = (__bf16)a[2]; r[3] = (__bf16)a[3];
  r[4] = (__bf16)b[0]; r[5] = (__bf16)b[1]; r[6] = (__bf16)b[2]; r[7] = (__bf16)b[3];
  return r;
}

// ---------------------------------------------------------------------------
// K0: mf_W f32 [512][1000] -> bf16 padded [512][1024]
// ---------------------------------------------------------------------------
__global__ __launch_bounds__(256) void k_prep(
    const float* __restrict__ mf_W, uint16_t* __restrict__ mfWb) {
  const int idx = blockIdx.x * 256 + threadIdx.x;   // 524288 total
  const int h = idx >> 10, k = idx & 1023;
  const float v = (k < 1000) ? mf_W[(size_t)h * 1000 + k] : 0.f;
  mfWb[idx] = f2bf(v);
}

// ---------------------------------------------------------------------------
// K1: encWb[v][col] = bf16( sum_k enc_emb[v][k]*W_ih[col][k] + b_ih + b_hh )
// ---------------------------------------------------------------------------
__global__ __launch_bounds__(256) void k_encW(
    const float* __restrict__ enc_emb,   // [1002][512]
    const float* __restrict__ W_ih,      // [2048][512]
    const float* __restrict__ b_ih,
    const float* __restrict__ b_hh,
    uint16_t* __restrict__ encWb)        // [1002][2048] bf16
{
  const int w = threadIdx.x >> 6, l = threadIdx.x & 63;
  const int mblk = blockIdx.x & 15;
  const int nblk = blockIdx.x >> 4;
  const int kg = l >> 4;
  const int arow = mblk * 64 + w * 16 + (l & 15);
  const bool rowok = arow < 1002;

  f32x4 acc[4] = {};
  for (int kk = 0; kk < 16; ++kk) {
    const int kc = kk * 32 + kg * 8;
    bf16x8 a = {};
    if (rowok) a = cvt8(enc_emb + (size_t)arow * 512 + kc);
#pragma unroll
    for (int n = 0; n < 4; ++n) {
      const int wrow = nblk * 64 + n * 16 + (l & 15);
      bf16x8 b = cvt8(W_ih + (size_t)wrow * 512 + kc);
      acc[n] = MFMA16(a, b, acc[n]);
    }
  }
  const int orow = mblk * 64 + w * 16 + kg * 4;
#pragma unroll
  for (int n = 0; n < 4; ++n) {
    const int col = nblk * 64 + n * 16 + (l & 15);
    const float bias = b_ih[col] + b_hh[col];
#pragma unroll
    for (int j = 0; j < 4; ++j) {
      const int rrow = orow + j;
      if (rrow < 1002) encWb[(size_t)rrow * 2048 + col] = f2bf(acc[n][j] + bias);
    }
  }
}

// ---------------------------------------------------------------------------
// K2: ext GEMM — RESTRUCTURED. Old version had 64 __syncthreads (2 per 32-k
//     tile) with only 128B/row staged between them: global-load latency sat
//     inside every barrier window (~64 x ~700cy serial). Now: stage a full
//     512-k half (64 rows x 512 k, f32->bf16, XOR-swizzled 64KB LDS — same
//     swizzle as k_scan's htgS) as one long independent load stream, then an
//     uninterrupted 512-MFMA sweep. Barriers 64 -> 4. 64KB LDS => 2 blocks/CU
//     so one block's staging overlaps the other's MFMA phase.
// ---------------------------------------------------------------------------
__global__ __launch_bounds__(256, 2) void k_ext(
    const int* __restrict__ uid, const int* __restrict__ sid,   // [51200]
    const float* __restrict__ user_emb,    // [50000][500]
    const float* __restrict__ skill_emb,   // [500][500]
    const uint16_t* __restrict__ mfWb,     // [512][1024] bf16
    const float* __restrict__ mf_b,        // [512]
    uint16_t* __restrict__ ext)            // [51200][512] bf16
{
  __shared__ uint16_t As[64 * 512];   // 65,536 B; rows of 1024B, XOR-swizzled

  const int tid = threadIdx.x;
  const int w = tid >> 6, l = tid & 63, kg = l >> 4;
  const int mblk = blockIdx.x;

  // staging role: 4 threads per row, 128 consecutive k each
  const int srow = tid >> 2;
  const int q = tid & 3;
  const int m = mblk * 64 + srow;
  const float* up = user_emb + (size_t)uid[m] * 500;
  const float* sp = skill_emb + (size_t)sid[m] * 500;

  f32x4 acc[4][8] = {};

#pragma unroll
  for (int ks = 0; ks < 2; ++ks) {
    if (ks) __syncthreads();   // As reused: wait for compute on half 0
    // ---- stage 64 rows x 512 k (f32 -> bf16), 16 chunks of 8 per thread
#pragma unroll
    for (int j = 0; j < 16; ++j) {
      const int e0 = ks * 512 + q * 128 + j * 8;   // global k, multiple of 8
      bf16x8 av = {};
      if (e0 + 8 <= 500) {                 // fully user
        av = cvt8(up + e0);
      } else if (e0 == 496) {              // straddle 496..503
        f32x4 a4 = *(const f32x4*)(up + 496);
        f32x4 b4 = *(const f32x4*)sp;
        av[0] = (__bf16)a4[0]; av[1] = (__bf16)a4[1]; av[2] = (__bf16)a4[2]; av[3] = (__bf16)a4[3];
        av[4] = (__bf16)b4[0]; av[5] = (__bf16)b4[1]; av[6] = (__bf16)b4[2]; av[7] = (__bf16)b4[3];
      } else if (e0 + 8 <= 1000) {         // fully skill (16B-aligned: e0%4==0)
        av = cvt8(sp + (e0 - 500));
      }                                    // e0 >= 1000: zero pad
      const int kb = (q * 128 + j * 8) * 2;          // byte offset in row
      *(bf16x8*)((char*)As + srow * 1024 + (kb ^ ((srow & 7) << 4))) = av;
    }
    __syncthreads();

    // ---- 16 x 32-k tiles: 32 MFMA each, no barriers inside
    for (int kk = 0; kk < 16; ++kk) {
      bf16x8 a[4];
#pragma unroll
      for (int rf = 0; rf < 4; ++rf) {
        const int row = rf * 16 + (l & 15);
        a[rf] = *(const bf16x8*)((char*)As + row * 1024 +
                                 ((kk * 64 + kg * 16) ^ ((row & 7) << 4)));
      }
#pragma unroll
      for (int n = 0; n < 8; ++n) {
        const int col = w * 128 + n * 16 + (l & 15);
        bf16x8 b = *(const bf16x8*)(mfWb + (size_t)col * 1024 + ks * 512 + kk * 32 + kg * 8);
#pragma unroll
        for (int rf = 0; rf < 4; ++rf)
          acc[rf][n] = MFMA16(a[rf], b, acc[rf][n]);
      }
    }
  }

#pragma unroll
  for (int rf = 0; rf < 4; ++rf)
#pragma unroll
    for (int n = 0; n < 8; ++n) {
      const int col = w * 128 + n * 16 + (l & 15);
      const float bias = mf_b[col];
#pragma unroll
      for (int j = 0; j < 4; ++j) {
        const int grow = mblk * 64 + rf * 16 + kg * 4 + j;
        ext[(size_t)grow * 512 + col] = f2bf(acc[rf][n][j] + bias);
      }
    }
}

// ---------------------------------------------------------------------------
// K3: persistent LSTM scan — byte-identical to ROUND 8 (730us, verified).
//     Flag protocol + per-wave incremental gather; agent-scope relaxed ops.
//     (Round-9 XCD fast path abandoned: unverifiable XCC_ID probe -> false
//     co-location -> cross-XCD stale-L2 deadlock.)
// ---------------------------------------------------------------------------
__global__ __launch_bounds__(256, 1) void k_scan(
    const int* __restrict__ inp,        // [256][200]
    const float* __restrict__ W_hh,     // [2048][512] f32
    const uint16_t* __restrict__ encWb, // [1002][2048] bf16
    const uint16_t* __restrict__ ext,   // [256*200][512] bf16
    uint16_t* __restrict__ hbuf,        // [2][256][512] bf16
    float* __restrict__ hfinal,         // [256][512] f32
    uint32_t* __restrict__ flags)       // [256] x 16-u32 stride (64B lines)
{
  __shared__ uint16_t htgS[16 * 512];   // XOR-swizzled rows of 1024B
  __shared__ float gbuf[4][16][32];
  __shared__ float ctS[16][32];
  __shared__ int inpS[16][200];

  const int tid = threadIdx.x;
  const int w = tid >> 6, l = tid & 63;   // wave w = gate (i,f,g,o)
  const int c = blockIdx.x & 15;          // h-slice (32 h)
  const int r = blockIdx.x >> 4;          // rowgroup (16 batch rows)
  const int row0 = r * 16;
  const int kg = l >> 4;

  // W_hh slice -> bf16 register fragments (persistent, 128 VGPRs)
  bf16x8 wfrag[16][2];
#pragma unroll
  for (int kk = 0; kk < 16; ++kk) {
#pragma unroll
    for (int n = 0; n < 2; ++n) {
      const int wrow = w * 512 + c * 32 + n * 16 + (l & 15);
      wfrag[kk][n] = cvt8(W_hh + (size_t)wrow * 512 + kk * 32 + kg * 8);
    }
  }
  for (int e = tid; e < 512; e += 256) ctS[e >> 5][e & 31] = 0.f;
  // htg(0) = 0 (h0 = 0): zero LDS directly
  for (int e = tid; e < 2048; e += 256) ((uint64_t*)htgS)[e] = 0ull;
  for (int e = tid; e < 16 * 200; e += 256)
    inpS[e / 200][e % 200] = inp[(row0 + e / 200) * 200 + (e % 200)];

  // gather role (within wave): row grow_, 16B chunk gch of a producer's 64B row-slice
  const int grow_ = l >> 2;             // 16 rows
  const int gch = l & 3;                // 4 x 16B chunks
  // cell role: row urr, 2 consecutive h
  const int urr = tid >> 4;
  const int uh2 = (tid & 15) << 1;
  const int ub = row0 + urr;

  __syncthreads();

  // ---- prologue prefetch: acc(t=0) from encWb, ext word for t=1 gate
  f32x4 acc[2];
#pragma unroll
  for (int n = 0; n < 2; ++n)
#pragma unroll
    for (int j = 0; j < 4; ++j) {
      const int col = w * 512 + c * 32 + n * 16 + (l & 15);
      acc[n][j] = bf2f(encWb[(size_t)inpS[kg * 4 + j][0] * 2048 + col]);
    }
  uint32_t ep = *(const uint32_t*)(ext + (size_t)ub * 200 * 512 + 512 + c * 32 + uh2);

  for (int t = 0; t < 200; ++t) {
    // ---- per-wave incremental gather of h(t): wave w owns producers 4w..4w+3
    if (t > 0) {
      const uint16_t* hb = hbuf + (size_t)(t & 1) * (256 * 512);
      uint64_t v[4][2];
#pragma unroll
      for (int p = 0; p < 4; ++p) {
        const int prod = w * 4 + p;
        // poll this producer's flag (all lanes same addr -> 1 request/wave)
        while (__hip_atomic_load(flags + (r * 16 + prod) * 16,
                                 __ATOMIC_RELAXED, __HIP_MEMORY_SCOPE_AGENT) < (uint32_t)t)
          __builtin_amdgcn_s_sleep(1);
        // issue this producer's 16B/lane gather (completes under later polls)
        const uint16_t* sp = hb + (size_t)(row0 + grow_) * 512 + prod * 32 + gch * 8;
        v[p][0] = __hip_atomic_load((const uint64_t*)sp,     __ATOMIC_RELAXED, __HIP_MEMORY_SCOPE_AGENT);
        v[p][1] = __hip_atomic_load((const uint64_t*)sp + 1, __ATOMIC_RELAXED, __HIP_MEMORY_SCOPE_AGENT);
      }
      // swizzled LDS writes (bank pattern: 2-way max = free)
#pragma unroll
      for (int p = 0; p < 4; ++p) {
        const int prod = w * 4 + p;
        const int baddr = grow_ * 1024 + (((prod * 64) + gch * 16) ^ ((grow_ & 7) << 4));
        *(uint64_t*)((char*)htgS + baddr)     = v[p][0];
        *(uint64_t*)((char*)htgS + baddr + 8) = v[p][1];
      }
    }
    __syncthreads();

    // ---- gates = acc(prefetched encW) + htg @ W_hh_slice^T
    const int ar = l & 15;
#pragma unroll
    for (int kk = 0; kk < 16; ++kk) {
      bf16x8 a = *(const bf16x8*)((char*)htgS + ar * 1024 +
                                  ((kk * 64 + kg * 16) ^ ((ar & 7) << 4)));
      acc[0] = MFMA16(a, wfrag[kk][0], acc[0]);
      acc[1] = MFMA16(a, wfrag[kk][1], acc[1]);
    }
#pragma unroll
    for (int n = 0; n < 2; ++n)
#pragma unroll
      for (int j = 0; j < 4; ++j)
        gbuf[w][kg * 4 + j][n * 16 + (l & 15)] = acc[n][j];
    __syncthreads();

    // ---- cell update: thread -> (row urr, 2 consecutive h)
    {
      float hv[2];
#pragma unroll
      for (int p = 0; p < 2; ++p) {
        const int h = uh2 + p;
        const float ig = sigf(gbuf[0][urr][h]);
        const float fg = sigf(gbuf[1][urr][h]);
        const float gg = tanhfast(gbuf[2][urr][h]);
        const float og = sigf(gbuf[3][urr][h]);
        const float cv = fg * ctS[urr][h] + ig * gg;
        ctS[urr][h] = cv;
        hv[p] = og * tanhfast(cv);
      }
      if (t < 199) {
        // pre-gate for step t+1: htg = ht * sigmoid(ext[:, t+1, :])
        const float g0 = sigf(bf2f((uint16_t)(ep & 0xFFFFu)));
        const float g1 = sigf(bf2f((uint16_t)(ep >> 16)));
        const uint32_t pk = (uint32_t)f2bf(hv[0] * g0) | ((uint32_t)f2bf(hv[1] * g1) << 16);
        uint32_t* hw = (uint32_t*)(hbuf + (size_t)((t + 1) & 1) * (256 * 512) +
                                   (size_t)ub * 512 + c * 32 + uh2);
        __hip_atomic_store(hw, pk, __ATOMIC_RELAXED, __HIP_MEMORY_SCOPE_AGENT);
      } else {
        hfinal[(size_t)ub * 512 + c * 32 + uh2]     = hv[0];
        hfinal[(size_t)ub * 512 + c * 32 + uh2 + 1] = hv[1];
      }
    }
    // all waves drain stores to the coherence point, then one flag store
    asm volatile("s_waitcnt vmcnt(0)" ::: "memory");
    __syncthreads();
    if (tid == 0)
      __hip_atomic_store(flags + (r * 16 + c) * 16, (uint32_t)(t + 1),
                         __ATOMIC_RELAXED, __HIP_MEMORY_SCOPE_AGENT);

    // ---- prefetch for step t+1 (off the signal path; hides under next poll)
    if (t < 199) {
      const int tn = t + 1;
#pragma unroll
      for (int n = 0; n < 2; ++n)
#pragma unroll
        for (int j = 0; j < 4; ++j) {
          const int col = w * 512 + c * 32 + n * 16 + (l & 15);
          acc[n][j] = bf2f(encWb[(size_t)inpS[kg * 4 + j][tn] * 2048 + col]);
        }
      const int te = (t + 2 < 200) ? t + 2 : 199;
      ep = *(const uint32_t*)(ext + (size_t)ub * 200 * 512 + (size_t)te * 512 + c * 32 + uh2);
    }
  }
}

// ---------------------------------------------------------------------------
// K4: out[b] = sigmoid( dot(hfinal[b], dec_W[tgt[b]]) + dec_b[tgt[b]] )
// ---------------------------------------------------------------------------
__global__ __launch_bounds__(256) void k_dec(
    const float* __restrict__ hfinal,   // [256][512]
    const float* __restrict__ dec_W,    // [500][512]
    const float* __restrict__ dec_b,    // [500]
    const int* __restrict__ tgt,        // [256]
    float* __restrict__ out)            // [256]
{
  const int w = threadIdx.x >> 6, l = threadIdx.x & 63;
  const int b = blockIdx.x * 4 + w;
  const int t = tgt[b];
  float s = 0.f;
#pragma unroll
  for (int i = 0; i < 8; ++i) {
    const int k = l + i * 64;
    s += hfinal[(size_t)b * 512 + k] * dec_W[(size_t)t * 512 + k];
  }
#pragma unroll
  for (int m = 32; m; m >>= 1) s += __shfl_xor(s, m, 64);
  if (l == 0) out[b] = sigf(s + dec_b[t]);
}

// ---------------------------------------------------------------------------
extern "C" void kernel_launch(void* const* d_in, const int* in_sizes, int n_in,
                              void* d_out, int out_size, void* d_ws, size_t ws_size,
                              hipStream_t stream) {
  (void)in_sizes; (void)n_in; (void)out_size; (void)ws_size;
  const int*   inp       = (const int*)d_in[0];
  const int*   target_id = (const int*)d_in[1];
  const int*   uid       = (const int*)d_in[2];
  const int*   sid       = (const int*)d_in[3];
  // d_in[4] attempt_sequence: unused by reference
  const float* enc_emb   = (const float*)d_in[5];
  const float* user_emb  = (const float*)d_in[6];
  const float* skill_emb = (const float*)d_in[7];
  const float* mf_W      = (const float*)d_in[8];
  const float* mf_b      = (const float*)d_in[9];
  const float* W_ih      = (const float*)d_in[10];
  const float* W_hh      = (const float*)d_in[11];
  const float* b_ih      = (const float*)d_in[12];
  const float* b_hh      = (const float*)d_in[13];
  const float* dec_W     = (const float*)d_in[14];
  const float* dec_b     = (const float*)d_in[15];

  char* ws = (char*)d_ws;
  uint32_t* flags  = (uint32_t*)(ws);                  //    16,384 B (padded flags)
  uint16_t* hbuf   = (uint16_t*)(ws + 16384);          //   524,288 B (bf16 x2 buf)
  float*    hfinal = (float*)   (ws + 540672);         //   524,288 B
  uint16_t* encWb  = (uint16_t*)(ws + 1064960);        // 4,104,192 B (bf16)
  uint16_t* mfWb   = (uint16_t*)(ws + 5169152);        // 1,048,576 B
  uint16_t* ext    = (uint16_t*)(ws + 6217728);        // 52,428,800 B (total ~58.6 MB)

  // zero flags every call (in-graph => every replay). hbuf needs no init:
  // gathers are gated by this-run flags; producers write full slices first.
  hipMemsetAsync(flags, 0, 16384, stream);

  k_prep<<<2048, 256, 0, stream>>>(mf_W, mfWb);
  k_encW<<<512,  256, 0, stream>>>(enc_emb, W_ih, b_ih, b_hh, encWb);
  k_ext <<<800,  256, 0, stream>>>(uid, sid, user_emb, skill_emb, mfWb, mf_b, ext);
  k_scan<<<256,  256, 0, stream>>>(inp, W_hh, encWb, ext, hbuf, hfinal, flags);
  k_dec <<<64,   256, 0, stream>>>(hfinal, dec_W, dec_b, target_id, (float*)d_out);
}

// Round 11
// 897.180 us; speedup vs baseline: 2.0162x; 1.0286x over previous
//
#include <hip/hip_runtime.h>
#include <stdint.h>

typedef __bf16 bf16x8 __attribute__((ext_vector_type(8)));
typedef float f32x4 __attribute__((ext_vector_type(4)));

#define MFMA16(a, b, c) __builtin_amdgcn_mfma_f32_16x16x32_bf16((a), (b), (c), 0, 0, 0)

__device__ __forceinline__ float sigf(float x) { return 1.f / (1.f + __expf(-x)); }
__device__ __forceinline__ float tanhfast(float x) { return 1.f - 2.f / (__expf(2.f * x) + 1.f); }
__device__ __forceinline__ float bf2f(uint16_t u) {
  union { float f; uint32_t i; } v; v.i = ((uint32_t)u) << 16; return v.f;
}
__device__ __forceinline__ uint16_t f2bf(float f) {
  union { float f; uint32_t i; } v; v.f = f;
  return (uint16_t)((v.i + 0x7FFFu + ((v.i >> 16) & 1u)) >> 16);
}
// 8 consecutive f32 -> bf16x8 (RNE); p must be 16B-aligned
__device__ __forceinline__ bf16x8 cvt8(const float* __restrict__ p) {
  f32x4 a = *(const f32x4*)p;
  f32x4 b = *(const f32x4*)(p + 4);
  bf16x8 r;
  r[0] = (__bf16)a[0]; r[1] = (__bf16)a[1]; r[2] = (__bf16)a[2]; r[3] = (__bf16)a[3];
  r[4] = (__bf16)b[0]; r[5] = (__bf16)b[1]; r[6] = (__bf16)b[2]; r[7] = (__bf16)b[3];
  return r;
}

// ---------------------------------------------------------------------------
// K0: mf_W f32 [512][1000] -> bf16 padded [512][1024]
// ---------------------------------------------------------------------------
__global__ __launch_bounds__(256) void k_prep(
    const float* __restrict__ mf_W, uint16_t* __restrict__ mfWb) {
  const int idx = blockIdx.x * 256 + threadIdx.x;   // 524288 total
  const int h = idx >> 10, k = idx & 1023;
  const float v = (k < 1000) ? mf_W[(size_t)h * 1000 + k] : 0.f;
  mfWb[idx] = f2bf(v);
}

// ---------------------------------------------------------------------------
// K1: encWb[v][col] = bf16( sum_k enc_emb[v][k]*W_ih[col][k] + b_ih + b_hh )
// ---------------------------------------------------------------------------
__global__ __launch_bounds__(256) void k_encW(
    const float* __restrict__ enc_emb,   // [1002][512]
    const float* __restrict__ W_ih,      // [2048][512]
    const float* __restrict__ b_ih,
    const float* __restrict__ b_hh,
    uint16_t* __restrict__ encWb)        // [1002][2048] bf16
{
  const int w = threadIdx.x >> 6, l = threadIdx.x & 63;
  const int mblk = blockIdx.x & 15;
  const int nblk = blockIdx.x >> 4;
  const int kg = l >> 4;
  const int arow = mblk * 64 + w * 16 + (l & 15);
  const bool rowok = arow < 1002;

  f32x4 acc[4] = {};
  for (int kk = 0; kk < 16; ++kk) {
    const int kc = kk * 32 + kg * 8;
    bf16x8 a = {};
    if (rowok) a = cvt8(enc_emb + (size_t)arow * 512 + kc);
#pragma unroll
    for (int n = 0; n < 4; ++n) {
      const int wrow = nblk * 64 + n * 16 + (l & 15);
      bf16x8 b = cvt8(W_ih + (size_t)wrow * 512 + kc);
      acc[n] = MFMA16(a, b, acc[n]);
    }
  }
  const int orow = mblk * 64 + w * 16 + kg * 4;
#pragma unroll
  for (int n = 0; n < 4; ++n) {
    const int col = nblk * 64 + n * 16 + (l & 15);
    const float bias = b_ih[col] + b_hh[col];
#pragma unroll
    for (int j = 0; j < 4; ++j) {
      const int rrow = orow + j;
      if (rrow < 1002) encWb[(size_t)rrow * 2048 + col] = f2bf(acc[n][j] + bias);
    }
  }
}

// ---------------------------------------------------------------------------
// K2-FUSED: blocks 0..255 = round-10 scan (verified 731us); blocks 256..1055 =
//     round-10 ext GEMM, remapped S-MAJOR (block -> one timestep x 64 batches)
//     and gated: ext epilogue = plain stores -> vmcnt(0) -> barrier ->
//     buffer_wbl2 sc1 (agent-release writeback, the exact op LLVM emits for
//     release-agent fences) -> extCnt[s] agent add. Scan gates only its ep
//     prefetch (ext[:,te], read 2 steps ahead) on extCnt[te]>=4 via agent
//     loads (cache-bypass => no stale lines). ext runs in the scan's idle
//     86% (28 free wave slots, 121KB free LDS per CU).
//     Deadlock-free under ANY dispatch order: ext blocks depend on nothing;
//     scan spins yield via s_sleep; LDS 64+64<=160KB and launch_bounds(256,2)
//     (VGPR<=256) guarantee an ext block can co-reside with a scan block.
// ---------------------------------------------------------------------------
__global__ __launch_bounds__(256, 2) void k_fused(
    const int* __restrict__ inp,        // [256][200]
    const float* __restrict__ W_hh,     // [2048][512] f32
    const uint16_t* __restrict__ encWb, // [1002][2048] bf16
    const int* __restrict__ uid, const int* __restrict__ sid,   // [51200]
    const float* __restrict__ user_emb,    // [50000][500]
    const float* __restrict__ skill_emb,   // [500][500]
    const uint16_t* __restrict__ mfWb,     // [512][1024] bf16
    const float* __restrict__ mf_b,        // [512]
    uint16_t* __restrict__ ext,         // [256*200][512] bf16
    uint16_t* __restrict__ hbuf,        // [2][256][512] bf16
    float* __restrict__ hfinal,         // [256][512] f32
    uint32_t* __restrict__ flags,       // [256] x 16-u32 stride (64B lines)
    uint32_t* __restrict__ extCnt)      // [200] x 16-u32 stride (64B lines)
{
  __shared__ __align__(1024) char ldsbuf[65536];

  const int tid = threadIdx.x;
  const int w = tid >> 6, l = tid & 63, kg = l >> 4;

  if (blockIdx.x >= 256) {
    // ================= EXT role (s-major) =================
    char* As = ldsbuf;   // [64 rows][1024B], XOR-swizzled
    const int bx = blockIdx.x - 256;
    const int s  = bx >> 2;      // timestep 0..199 (early s dispatch first)
    const int bq = bx & 3;       // batch quarter

    // staging role: 4 threads per row (row = local batch), 128 consecutive k
    const int srow = tid >> 2;
    const int q = tid & 3;
    const int m = (bq * 64 + srow) * 200 + s;
    const float* up = user_emb + (size_t)uid[m] * 500;
    const float* sp = skill_emb + (size_t)sid[m] * 500;

    f32x4 acc[4][8] = {};

#pragma unroll
    for (int ks = 0; ks < 2; ++ks) {
      if (ks) __syncthreads();   // As reused
#pragma unroll
      for (int j = 0; j < 16; ++j) {
        const int e0 = ks * 512 + q * 128 + j * 8;
        bf16x8 av = {};
        if (e0 + 8 <= 500) {
          av = cvt8(up + e0);
        } else if (e0 == 496) {
          f32x4 a4 = *(const f32x4*)(up + 496);
          f32x4 b4 = *(const f32x4*)sp;
          av[0] = (__bf16)a4[0]; av[1] = (__bf16)a4[1]; av[2] = (__bf16)a4[2]; av[3] = (__bf16)a4[3];
          av[4] = (__bf16)b4[0]; av[5] = (__bf16)b4[1]; av[6] = (__bf16)b4[2]; av[7] = (__bf16)b4[3];
        } else if (e0 + 8 <= 1000) {
          av = cvt8(sp + (e0 - 500));
        }
        const int kb = (q * 128 + j * 8) * 2;
        *(bf16x8*)(As + srow * 1024 + (kb ^ ((srow & 7) << 4))) = av;
      }
      __syncthreads();

      for (int kk = 0; kk < 16; ++kk) {
        bf16x8 a[4];
#pragma unroll
        for (int rf = 0; rf < 4; ++rf) {
          const int row = rf * 16 + (l & 15);
          a[rf] = *(const bf16x8*)(As + row * 1024 +
                                   ((kk * 64 + kg * 16) ^ ((row & 7) << 4)));
        }
#pragma unroll
        for (int n = 0; n < 8; ++n) {
          const int col = w * 128 + n * 16 + (l & 15);
          bf16x8 b = *(const bf16x8*)(mfWb + (size_t)col * 1024 + ks * 512 + kk * 32 + kg * 8);
#pragma unroll
          for (int rf = 0; rf < 4; ++rf)
            acc[rf][n] = MFMA16(a[rf], b, acc[rf][n]);
        }
      }
    }

    // epilogue: plain stores (write-back L2) ...
#pragma unroll
    for (int rf = 0; rf < 4; ++rf)
#pragma unroll
      for (int n = 0; n < 8; ++n) {
        const int col = w * 128 + n * 16 + (l & 15);
        const float bias = mf_b[col];
#pragma unroll
        for (int j = 0; j < 4; ++j) {
          const int bl = rf * 16 + kg * 4 + j;          // local batch row
          const size_t grow = (size_t)(bq * 64 + bl) * 200 + s;
          ext[grow * 512 + col] = f2bf(acc[rf][n][j] + bias);
        }
      }
    // ... then publish: ack into L2, all waves done, L2->LLC writeback, count.
    asm volatile("s_waitcnt vmcnt(0)" ::: "memory");
    __syncthreads();
    if (tid == 0) {
      asm volatile("buffer_wbl2 sc1\n\ts_waitcnt vmcnt(0)" ::: "memory");
      __hip_atomic_fetch_add(extCnt + s * 16, 1u, __ATOMIC_RELAXED, __HIP_MEMORY_SCOPE_AGENT);
    }
    return;
  }

  // ================= SCAN role (round-8/10 proven protocol) =================
  uint16_t* htgS       = (uint16_t*)ldsbuf;               // 16,384 B swizzled
  float (*gbuf)[16][32] = (float(*)[16][32])(ldsbuf + 16384);  // 8,192 B
  float (*ctS)[32]      = (float(*)[32])(ldsbuf + 24576);      // 2,048 B
  int (*inpS)[200]      = (int(*)[200])(ldsbuf + 26624);       // 12,800 B

  const int c = blockIdx.x & 15;          // h-slice (32 h)
  const int r = blockIdx.x >> 4;          // rowgroup (16 batch rows)
  const int row0 = r * 16;

  // W_hh slice -> bf16 register fragments (persistent, 128 VGPRs)
  bf16x8 wfrag[16][2];
#pragma unroll
  for (int kk = 0; kk < 16; ++kk) {
#pragma unroll
    for (int n = 0; n < 2; ++n) {
      const int wrow = w * 512 + c * 32 + n * 16 + (l & 15);
      wfrag[kk][n] = cvt8(W_hh + (size_t)wrow * 512 + kk * 32 + kg * 8);
    }
  }
  for (int e = tid; e < 512; e += 256) ctS[e >> 5][e & 31] = 0.f;
  for (int e = tid; e < 2048; e += 256) ((uint64_t*)htgS)[e] = 0ull;   // htg(0)=0
  for (int e = tid; e < 16 * 200; e += 256)
    inpS[e / 200][e % 200] = inp[(row0 + e / 200) * 200 + (e % 200)];

  const int grow_ = l >> 2;             // gather: row, 16B chunk
  const int gch = l & 3;
  const int urr = tid >> 4;             // cell: row, 2 consecutive h
  const int uh2 = (tid & 15) << 1;
  const int ub = row0 + urr;

  __syncthreads();

  // ---- prologue: acc(t=0) from encWb; gated ep (ext[:,1]) via agent load
  f32x4 acc[2];
#pragma unroll
  for (int n = 0; n < 2; ++n)
#pragma unroll
    for (int j = 0; j < 4; ++j) {
      const int col = w * 512 + c * 32 + n * 16 + (l & 15);
      acc[n][j] = bf2f(encWb[(size_t)inpS[kg * 4 + j][0] * 2048 + col]);
    }
  while (__hip_atomic_load(extCnt + 16, __ATOMIC_RELAXED, __HIP_MEMORY_SCOPE_AGENT) < 4u)
    __builtin_amdgcn_s_sleep(1);
  uint32_t ep = __hip_atomic_load(
      (const uint32_t*)(ext + (size_t)ub * 200 * 512 + 512 + c * 32 + uh2),
      __ATOMIC_RELAXED, __HIP_MEMORY_SCOPE_AGENT);

  for (int t = 0; t < 200; ++t) {
    // ---- per-wave incremental gather of h(t): wave w owns producers 4w..4w+3
    if (t > 0) {
      const uint16_t* hb = hbuf + (size_t)(t & 1) * (256 * 512);
      uint64_t v[4][2];
#pragma unroll
      for (int p = 0; p < 4; ++p) {
        const int prod = w * 4 + p;
        while (__hip_atomic_load(flags + (r * 16 + prod) * 16,
                                 __ATOMIC_RELAXED, __HIP_MEMORY_SCOPE_AGENT) < (uint32_t)t)
          __builtin_amdgcn_s_sleep(1);
        const uint16_t* sp = hb + (size_t)(row0 + grow_) * 512 + prod * 32 + gch * 8;
        v[p][0] = __hip_atomic_load((const uint64_t*)sp,     __ATOMIC_RELAXED, __HIP_MEMORY_SCOPE_AGENT);
        v[p][1] = __hip_atomic_load((const uint64_t*)sp + 1, __ATOMIC_RELAXED, __HIP_MEMORY_SCOPE_AGENT);
      }
#pragma unroll
      for (int p = 0; p < 4; ++p) {
        const int prod = w * 4 + p;
        const int baddr = grow_ * 1024 + (((prod * 64) + gch * 16) ^ ((grow_ & 7) << 4));
        *(uint64_t*)((char*)htgS + baddr)     = v[p][0];
        *(uint64_t*)((char*)htgS + baddr + 8) = v[p][1];
      }
    }
    __syncthreads();

    // ---- gates = acc(prefetched encW) + htg @ W_hh_slice^T
    const int ar = l & 15;
#pragma unroll
    for (int kk = 0; kk < 16; ++kk) {
      bf16x8 a = *(const bf16x8*)((char*)htgS + ar * 1024 +
                                  ((kk * 64 + kg * 16) ^ ((ar & 7) << 4)));
      acc[0] = MFMA16(a, wfrag[kk][0], acc[0]);
      acc[1] = MFMA16(a, wfrag[kk][1], acc[1]);
    }
#pragma unroll
    for (int n = 0; n < 2; ++n)
#pragma unroll
      for (int j = 0; j < 4; ++j)
        gbuf[w][kg * 4 + j][n * 16 + (l & 15)] = acc[n][j];
    __syncthreads();

    // ---- cell update: thread -> (row urr, 2 consecutive h)
    {
      float hv[2];
#pragma unroll
      for (int p = 0; p < 2; ++p) {
        const int h = uh2 + p;
        const float ig = sigf(gbuf[0][urr][h]);
        const float fg = sigf(gbuf[1][urr][h]);
        const float gg = tanhfast(gbuf[2][urr][h]);
        const float og = sigf(gbuf[3][urr][h]);
        const float cv = fg * ctS[urr][h] + ig * gg;
        ctS[urr][h] = cv;
        hv[p] = og * tanhfast(cv);
      }
      if (t < 199) {
        // pre-gate for step t+1: htg = ht * sigmoid(ext[:, t+1, :])
        const float g0 = sigf(bf2f((uint16_t)(ep & 0xFFFFu)));
        const float g1 = sigf(bf2f((uint16_t)(ep >> 16)));
        const uint32_t pk = (uint32_t)f2bf(hv[0] * g0) | ((uint32_t)f2bf(hv[1] * g1) << 16);
        uint32_t* hw = (uint32_t*)(hbuf + (size_t)((t + 1) & 1) * (256 * 512) +
                                   (size_t)ub * 512 + c * 32 + uh2);
        __hip_atomic_store(hw, pk, __ATOMIC_RELAXED, __HIP_MEMORY_SCOPE_AGENT);
      } else {
        hfinal[(size_t)ub * 512 + c * 32 + uh2]     = hv[0];
        hfinal[(size_t)ub * 512 + c * 32 + uh2 + 1] = hv[1];
      }
    }
    // drain stores to coherence point, then one flag store
    asm volatile("s_waitcnt vmcnt(0)" ::: "memory");
    __syncthreads();
    if (tid == 0)
      __hip_atomic_store(flags + (r * 16 + c) * 16, (uint32_t)(t + 1),
                         __ATOMIC_RELAXED, __HIP_MEMORY_SCOPE_AGENT);

    // ---- prefetch for step t+1 (off signal path; ext gated 2 steps ahead)
    if (t < 199) {
      const int tn = t + 1;
#pragma unroll
      for (int n = 0; n < 2; ++n)
#pragma unroll
        for (int j = 0; j < 4; ++j) {
          const int col = w * 512 + c * 32 + n * 16 + (l & 15);
          acc[n][j] = bf2f(encWb[(size_t)inpS[kg * 4 + j][tn] * 2048 + col]);
        }
      const int te = (t + 2 < 200) ? t + 2 : 199;
      while (__hip_atomic_load(extCnt + te * 16, __ATOMIC_RELAXED, __HIP_MEMORY_SCOPE_AGENT) < 4u)
        __builtin_amdgcn_s_sleep(1);
      ep = __hip_atomic_load(
          (const uint32_t*)(ext + (size_t)ub * 200 * 512 + (size_t)te * 512 + c * 32 + uh2),
          __ATOMIC_RELAXED, __HIP_MEMORY_SCOPE_AGENT);
    }
  }
}

// ---------------------------------------------------------------------------
// K4: out[b] = sigmoid( dot(hfinal[b], dec_W[tgt[b]]) + dec_b[tgt[b]] )
// ---------------------------------------------------------------------------
__global__ __launch_bounds__(256) void k_dec(
    const float* __restrict__ hfinal,   // [256][512]
    const float* __restrict__ dec_W,    // [500][512]
    const float* __restrict__ dec_b,    // [500]
    const int* __restrict__ tgt,        // [256]
    float* __restrict__ out)            // [256]
{
  const int w = threadIdx.x >> 6, l = threadIdx.x & 63;
  const int b = blockIdx.x * 4 + w;
  const int t = tgt[b];
  float s = 0.f;
#pragma unroll
  for (int i = 0; i < 8; ++i) {
    const int k = l + i * 64;
    s += hfinal[(size_t)b * 512 + k] * dec_W[(size_t)t * 512 + k];
  }
#pragma unroll
  for (int m = 32; m; m >>= 1) s += __shfl_xor(s, m, 64);
  if (l == 0) out[b] = sigf(s + dec_b[t]);
}

// ---------------------------------------------------------------------------
extern "C" void kernel_launch(void* const* d_in, const int* in_sizes, int n_in,
                              void* d_out, int out_size, void* d_ws, size_t ws_size,
                              hipStream_t stream) {
  (void)in_sizes; (void)n_in; (void)out_size; (void)ws_size;
  const int*   inp       = (const int*)d_in[0];
  const int*   target_id = (const int*)d_in[1];
  const int*   uid       = (const int*)d_in[2];
  const int*   sid       = (const int*)d_in[3];
  // d_in[4] attempt_sequence: unused by reference
  const float* enc_emb   = (const float*)d_in[5];
  const float* user_emb  = (const float*)d_in[6];
  const float* skill_emb = (const float*)d_in[7];
  const float* mf_W      = (const float*)d_in[8];
  const float* mf_b      = (const float*)d_in[9];
  const float* W_ih      = (const float*)d_in[10];
  const float* W_hh      = (const float*)d_in[11];
  const float* b_ih      = (const float*)d_in[12];
  const float* b_hh      = (const float*)d_in[13];
  const float* dec_W     = (const float*)d_in[14];
  const float* dec_b     = (const float*)d_in[15];

  char* ws = (char*)d_ws;
  uint32_t* flags  = (uint32_t*)(ws);                  //    16,384 B (padded h-flags)
  uint32_t* extCnt = (uint32_t*)(ws + 16384);          //    12,800 B (padded s-counters)
  uint16_t* hbuf   = (uint16_t*)(ws + 32768);          //   524,288 B (bf16 x2 buf)
  float*    hfinal = (float*)   (ws + 557056);         //   524,288 B
  uint16_t* encWb  = (uint16_t*)(ws + 1081344);        // 4,104,192 B (bf16)
  uint16_t* mfWb   = (uint16_t*)(ws + 5185536);        // 1,048,576 B
  uint16_t* ext    = (uint16_t*)(ws + 6234112);        // 52,428,800 B (total ~58.7 MB)

  // zero flags + extCnt every call (in-graph => every replay)
  hipMemsetAsync(ws, 0, 29184, stream);

  k_prep<<<2048, 256, 0, stream>>>(mf_W, mfWb);
  k_encW<<<512,  256, 0, stream>>>(enc_emb, W_ih, b_ih, b_hh, encWb);
  k_fused<<<1056, 256, 0, stream>>>(inp, W_hh, encWb, uid, sid, user_emb, skill_emb,
                                    mfWb, mf_b, ext, hbuf, hfinal, flags, extCnt);
  k_dec<<<64, 256, 0, stream>>>(hfinal, dec_W, dec_b, target_id, (float*)d_out);
}